// Round 18
// baseline (189.419 us; speedup 1.0000x reference)
//
#include <hip/hip_runtime.h>

#define BQ 4
#define SQ 2048
#define DQ 1024
#define HQ 16
#define BHQ 64

typedef __attribute__((ext_vector_type(8))) short short8;
typedef __attribute__((ext_vector_type(4))) float f32x4;
typedef __attribute__((ext_vector_type(16))) float f32x16;
typedef __attribute__((ext_vector_type(2))) unsigned int u32x2;
typedef unsigned short u16;
typedef unsigned int u32;
typedef unsigned long long u64;

__device__ __forceinline__ u16 f2bf(float f) {
  u32 u = __float_as_uint(f);
  u32 r = u + 0x7fffu + ((u >> 16) & 1u);
  return (u16)(r >> 16);
}
__device__ __forceinline__ float bf2f(u16 h) {
  return __uint_as_float(((u32)h) << 16);
}

// packed f32x2 -> bf16x2 (RNE), one instruction
__device__ __forceinline__ u32 pkbf(float lo, float hi_) {
  u32 r;
  asm("v_cvt_pk_bf16_f32 %0, %1, %2" : "=v"(r) : "v"(lo), "v"(hi_));
  return r;
}
// raw v_exp_f32: computes 2^x (input already in log2 domain)
__device__ __forceinline__ float fexp2(float x) {
  float r;
  asm("v_exp_f32 %0, %1" : "=v"(r) : "v"(x));
  return r;
}
// cross-half exchange via shfl (known-correct)
__device__ __forceinline__ float xmax32(float x) { return fmaxf(x, __shfl_xor(x, 32)); }
__device__ __forceinline__ float xsum32(float x) { return x + __shfl_xor(x, 32); }
__device__ __forceinline__ u32 xword(u32 send) { return (u32)__shfl_xor((int)send, 32); }

// async global->LDS, 16B per lane. LDS dest must be wave-uniform; HW adds lane*16.
__device__ __forceinline__ void gload_lds16(const void* g, void* l) {
  __builtin_amdgcn_global_load_lds(
      (const __attribute__((address_space(1))) u32*)(unsigned long long)g,
      (__attribute__((address_space(3))) u32*)(u32)(unsigned long long)l,
      16, 0, 0);
}

// ---------------- fused prep: cvt x | transpose wqkv | transpose wout | rope tab | mflags ----------------
__device__ __forceinline__ void transpose_body(const float* __restrict__ in, u16* __restrict__ out,
                                               int R, int C, int bx, int by, int tid) {
  __shared__ float t[32][33];
  int c0 = bx * 32, r0 = by * 32;
  int tx = tid & 31, ty = tid >> 5;
  for (int rr = ty; rr < 32; rr += 8)
    t[rr][tx] = in[(size_t)(r0 + rr) * C + c0 + tx];
  __syncthreads();
  for (int rr = ty; rr < 32; rr += 8)
    out[(size_t)(c0 + rr) * R + r0 + tx] = f2bf(t[tx][rr]);
}

__global__ __launch_bounds__(256) void k_prep(const float* __restrict__ x, u16* __restrict__ xb,
                                              const float* __restrict__ wqkv, u16* __restrict__ wqkvT,
                                              const float* __restrict__ wout, u16* __restrict__ woutT,
                                              float* __restrict__ tab, const int* __restrict__ mask,
                                              u64* __restrict__ mbits) {
  int bid = blockIdx.x, tid = threadIdx.x;
  if (bid < 8192) {                       // cvt x -> bf16 (2M float4)
    int i = bid * 256 + tid;
    float4 v = ((const float4*)x)[i];
    ushort4 o;
    o.x = f2bf(v.x); o.y = f2bf(v.y); o.z = f2bf(v.z); o.w = f2bf(v.w);
    ((ushort4*)xb)[i] = o;
  } else if (bid < 11264) {               // transpose wqkv [1024][3072] -> [3072][1024]
    int t = bid - 8192;
    transpose_body(wqkv, wqkvT, 1024, 3072, t % 96, t / 96, tid);
  } else if (bid < 12288) {               // transpose wout [1024][1024]
    int t = bid - 11264;
    transpose_body(wout, woutT, 1024, 1024, t % 32, t / 32, tid);
  } else if (bid < 12544) {               // rope cos/sin table [S][32][2]
    int i = (bid - 12288) * 256 + tid;
    int s = i >> 5, dp = i & 31;
    float invf = expf(-0.28782313662425576f * (float)dp);
    float ang = (float)s * invf;
    tab[i * 2] = cosf(ang);
    tab[i * 2 + 1] = sinf(ang);
  } else {                                // mask bitmask (1 block: wave=batch, lane=chunk)
    int b = tid >> 6, c = tid & 63;
    int all1 = 1;
    for (int i = 0; i < 32; ++i) all1 &= (mask[b * SQ + c * 32 + i] != 0) ? 1 : 0;
    u64 m = __ballot(all1);
    if (c == 0) mbits[b] = m;
  }
}

// ---------------- GEMM-8phase (q,k portion): C = A[8192,1024] @ Bt[0..2048,1024]^T ----------------
// BM=BN=256, BK=32, 8 waves (2M x 4N, wave tile 128x64 = acc[8][4]). 3 LDS slots (96KB):
// counted vmcnt(4) per K-tile (tile t+1's 4 loads stay in flight - never drains to 0).
// Per K-tile: 2 phases {stage half of tile t+2 -> ds_read frags -> lgkmcnt(0) -> 16 MFMA},
// 2 barriers. LDS K-tile row-major [256][32]: frag reads cover 64 consecutive 16B slots
// (conflict-free) and staging is linear from xb/wqkvT. Grid 256 = 1 block/CU (uniform).
// Epilogue: fused RoPE, q -> qbuf linear, k -> kbuf tiled (flash12 layouts).
__global__ __launch_bounds__(512, 2) void k_gemm8(const u16* __restrict__ A, const u16* __restrict__ Bt,
                                                  u16* __restrict__ qb, u16* __restrict__ kb,
                                                  const float* __restrict__ tab) {
  __shared__ u16 ldsA[3][8192];
  __shared__ u16 ldsB[3][8192];
  int bid = blockIdx.x;
  int tn = bid & 7, tm = bid >> 3;   // XCD x hosts tn=x for all its blocks -> B L2-resident
  int tid = threadIdx.x, w = tid >> 6, l = tid & 63;
  int wm = w >> 2, wn = w & 3;
  int li = l & 15, lg = l >> 4;

  // staging lane sources: slot = instr*512 + w*64 + l; row = slot>>2, c16 = slot&3
  int sl0 = w * 64 + l, sl1 = sl0 + 512;
  const u16* aS0 = A + (size_t)(tm * 256 + (sl0 >> 2)) * 1024 + (sl0 & 3) * 8;
  const u16* aS1 = A + (size_t)(tm * 256 + (sl1 >> 2)) * 1024 + (sl1 & 3) * 8;
  const u16* bS0 = Bt + (size_t)(tn * 256 + (sl0 >> 2)) * 1024 + (sl0 & 3) * 8;
  const u16* bS1 = Bt + (size_t)(tn * 256 + (sl1 >> 2)) * 1024 + (sl1 & 3) * 8;

  f32x4 acc[8][4];
#pragma unroll
  for (int i = 0; i < 8; ++i)
#pragma unroll
    for (int j = 0; j < 4; ++j) acc[i][j] = (f32x4){0.f, 0.f, 0.f, 0.f};

  // prologue: stage tiles 0 (slot0) and 1 (slot1); 8 loads outstanding
  gload_lds16(aS0, &ldsA[0][w * 512]);
  gload_lds16(aS1, &ldsA[0][w * 512 + 4096]);
  gload_lds16(bS0, &ldsB[0][w * 512]);
  gload_lds16(bS1, &ldsB[0][w * 512 + 4096]);
  gload_lds16(aS0 + 32, &ldsA[1][w * 512]);
  gload_lds16(aS1 + 32, &ldsA[1][w * 512 + 4096]);
  gload_lds16(bS0 + 32, &ldsB[1][w * 512]);
  gload_lds16(bS1 + 32, &ldsB[1][w * 512 + 4096]);

  int s = 0;
  for (int t = 0; t < 32; ++t) {
    int s2 = s + 2; if (s2 >= 3) s2 -= 3;
    int tst = (t + 2 < 32) ? t + 2 : 31;   // tail: redundant re-stage keeps vmcnt uniform
    // tile t's 4 loads done; tile t+1's 4 stay in flight (counted, never 0)
    asm volatile("s_waitcnt vmcnt(4)" ::: "memory");
    __builtin_amdgcn_s_barrier();
    // stage A of tile t+2 into slot s2 (slot freed: last read at tile t-1)
    gload_lds16(aS0 + tst * 32, &ldsA[s2][w * 512]);
    gload_lds16(aS1 + tst * 32, &ldsA[s2][w * 512 + 4096]);

    const u16* As = ldsA[s];
    const u16* Bs = ldsB[s];
    short8 bf[4], af[4];
#pragma unroll
    for (int nf = 0; nf < 4; ++nf) bf[nf] = *(const short8*)&Bs[(wn * 64 + nf * 16 + li) * 32 + lg * 8];
#pragma unroll
    for (int m2 = 0; m2 < 4; ++m2) af[m2] = *(const short8*)&As[(wm * 128 + m2 * 16 + li) * 32 + lg * 8];
    asm volatile("s_waitcnt lgkmcnt(0)" ::: "memory");
    __builtin_amdgcn_sched_barrier(0);
    __builtin_amdgcn_s_setprio(1);
#pragma unroll
    for (int m2 = 0; m2 < 4; ++m2)
#pragma unroll
      for (int nf = 0; nf < 4; ++nf)
        acc[m2][nf] = __builtin_amdgcn_mfma_f32_16x16x32_bf16(af[m2], bf[nf], acc[m2][nf], 0, 0, 0);
    __builtin_amdgcn_s_setprio(0);

    __builtin_amdgcn_s_barrier();
    // stage B of tile t+2 into slot s2
    gload_lds16(bS0 + tst * 32, &ldsB[s2][w * 512]);
    gload_lds16(bS1 + tst * 32, &ldsB[s2][w * 512 + 4096]);

#pragma unroll
    for (int m2 = 0; m2 < 4; ++m2) af[m2] = *(const short8*)&As[(wm * 128 + 64 + m2 * 16 + li) * 32 + lg * 8];
    asm volatile("s_waitcnt lgkmcnt(0)" ::: "memory");
    __builtin_amdgcn_sched_barrier(0);
    __builtin_amdgcn_s_setprio(1);
#pragma unroll
    for (int m2 = 0; m2 < 4; ++m2)
#pragma unroll
      for (int nf = 0; nf < 4; ++nf)
        acc[4 + m2][nf] = __builtin_amdgcn_mfma_f32_16x16x32_bf16(af[m2], bf[nf], acc[4 + m2][nf], 0, 0, 0);
    __builtin_amdgcn_s_setprio(0);

    s = (s == 2) ? 0 : s + 1;
  }

  // epilogue: fused RoPE; wave owns one (which, h): 64 cols
  int ngb = tn * 256 + wn * 64;
  int which = ngb >> 10;              // 0=q, 1=k
  int h = (ngb >> 6) & 15;
  float scale = (which == 0) ? 0.125f * 1.44269504088896f : 1.0f;
#pragma unroll
  for (int mf = 0; mf < 8; ++mf) {
#pragma unroll
    for (int r = 0; r < 4; ++r) {
      int mg = tm * 256 + wm * 128 + mf * 16 + lg * 4 + r;
      int b = mg >> 11, sidx = mg & 2047;
#pragma unroll
      for (int nf2 = 0; nf2 < 2; ++nf2) {
        int dp = nf2 * 16 + li;       // 0..31; rope pair (dp, dp+32)
        float2 cs = *(const float2*)&tab[(sidx * 32 + dp) * 2];
        float a = acc[mf][nf2][r];
        float bb = acc[mf][nf2 + 2][r];
        float lo = (a * cs.x - bb * cs.y) * scale;
        float hi2 = (bb * cs.x + a * cs.y) * scale;
        if (which == 0) {
          u16* dst = qb + ((((size_t)b * HQ + h) * SQ + sidx) << 6);
          dst[dp] = f2bf(lo);
          dst[dp + 32] = f2bf(hi2);
        } else {
          u16* dst = kb + ((size_t)b * HQ + h) * (64 * 2048) + (sidx >> 5) * 2048 + (sidx & 31) * 8;
          dst[(dp >> 3) * 256 + (dp & 7)] = f2bf(lo);
          dst[(dp >> 3) * 256 + 1024 + (dp & 7)] = f2bf(hi2);  // d+32 -> slot+4
        }
      }
    }
  }
}

// ---------------- GEMM (old structure): C[M,N] = A[M,K](bf16) @ Bt[N,K]^T(bf16) ----------------
// BK=64, K-swizzled LDS, XCD-chunked map. tn = local + tnoff.
// EPI 0: write f32 C row-major. EPI 1: v-portion only (tnoff=16) -> tiled vTs scatter.
template <int EPI>
__global__ __launch_bounds__(256) void k_gemm(const u16* __restrict__ A, const u16* __restrict__ Bt,
                                              float* __restrict__ Cf, u16* __restrict__ vTs,
                                              int K, int tnoff) {
  __shared__ u16 lA[128 * 64];
  __shared__ u16 lB[128 * 64];
  int bid = blockIdx.x;
  int i_ = bid >> 3;
  int tm = (bid & 7) * 8 + (i_ & 7);
  int tn = (i_ >> 3) + tnoff;
  int tid = threadIdx.x, w = tid >> 6, l = tid & 63;
  int wm = w >> 1, wn = w & 1;
  int li = l & 15, lg = l >> 4;
  const u16* gA = A + (size_t)tm * 128 * K;
  const u16* gB = Bt + (size_t)tn * 128 * K;
  f32x4 acc[4][4];
#pragma unroll
  for (int i = 0; i < 4; i++)
#pragma unroll
    for (int j = 0; j < 4; j++) acc[i][j] = (f32x4){0.f, 0.f, 0.f, 0.f};

  int lr = l >> 3, lslot = l & 7;
  int scol = ((lslot ^ lr) * 8);

  for (int kt = 0; kt < K; kt += 64) {
    __syncthreads();
#pragma unroll
    for (int i = 0; i < 4; ++i) {
      int ch = i * 4 + w;
      int row = ch * 8 + lr;
      gload_lds16(gA + (size_t)row * K + kt + scol, &lA[ch * 512]);
      gload_lds16(gB + (size_t)row * K + kt + scol, &lB[ch * 512]);
    }
    __syncthreads();
#pragma unroll
    for (int kk = 0; kk < 2; ++kk) {
      short8 af[4], bfr[4];
#pragma unroll
      for (int mf = 0; mf < 4; ++mf) {
        int row = wm * 64 + mf * 16 + li;
        af[mf] = *(const short8*)&lA[row * 64 + (((kk * 4 + lg)) ^ (row & 7)) * 8];
      }
#pragma unroll
      for (int nf = 0; nf < 4; ++nf) {
        int row = wn * 64 + nf * 16 + li;
        bfr[nf] = *(const short8*)&lB[row * 64 + (((kk * 4 + lg)) ^ (row & 7)) * 8];
      }
#pragma unroll
      for (int mf = 0; mf < 4; ++mf)
#pragma unroll
        for (int nf = 0; nf < 4; ++nf)
          acc[mf][nf] = __builtin_amdgcn_mfma_f32_16x16x32_bf16(af[mf], bfr[nf], acc[mf][nf], 0, 0, 0);
    }
  }
  if (EPI == 0) {
#pragma unroll
    for (int mf = 0; mf < 4; ++mf) {
      int mg0 = tm * 128 + wm * 64 + mf * 16 + lg * 4;
#pragma unroll
      for (int nf = 0; nf < 4; ++nf) {
        int ng = tn * 128 + wn * 64 + nf * 16 + li;
#pragma unroll
        for (int r = 0; r < 4; ++r)
          Cf[(size_t)(mg0 + r) * 1024 + ng] = acc[mf][nf][r];
      }
    }
  } else {
    // v-portion (tn in [16,24)): tiled vTs [bh][kt][4 slot=k>>3][64 d][8 e]
    int h = (tn & 7) * 2 + wn;
    int b = tm >> 4;
#pragma unroll
    for (int mf = 0; mf < 4; ++mf) {
      int s0 = (tm * 128 + wm * 64 + mf * 16 + lg * 4) & 2047;
      int kt = s0 >> 5, kk0 = s0 & 31;
      size_t tb = (((size_t)(b * HQ + h) * 64 + kt) * 2048) + (kk0 >> 3) * 512 + (kk0 & 7);
#pragma unroll
      for (int nf = 0; nf < 4; ++nf) {
        int d = nf * 16 + li;
        u32 w0 = pkbf(acc[mf][nf][0], acc[mf][nf][1]);
        u32 w1 = pkbf(acc[mf][nf][2], acc[mf][nf][3]);
        *(u32x2*)&vTs[tb + d * 8] = (u32x2){w0, w1};
      }
    }
  }
}

// ---------------- flash v12 (80.7us verified): 2 k-tiles per barrier phase ----------------
__global__ __launch_bounds__(256) void k_flash12(const u16* __restrict__ Q, const u16* __restrict__ Kb,
                                                 const u16* __restrict__ VTs, const int* __restrict__ mask,
                                                 const u64* __restrict__ mbits, u16* __restrict__ O) {
  __shared__ alignas(16) u16 Kl[2][4096];
  __shared__ alignas(16) u16 Vl[2][4096];
  int bid = blockIdx.x;
  int bh = bid & 63;
  int u = bid >> 6, v = u & 3, k4 = u >> 2;
  int qsup = (k4 == 0) ? v : (k4 == 1) ? 7 - v : (k4 == 2) ? 8 + v : 15 - v;
  int tid = threadIdx.x, w = tid >> 6, l = tid & 63;
  int j = l & 31, hi = l >> 5;
  int myqt = qsup * 4 + w;
  int P = 2 * qsup + 2;
  int b = bh >> 4, h = bh & 15;
  const int* mp = mask + b * SQ + 4 * hi;
  u64 mb = mbits[b];

  const u16* Kg0 = Kb + (size_t)bh * (64 * 2048) + tid * 8;
  const u16* Vg0 = VTs + (size_t)bh * (64 * 2048) + tid * 8;
  u16* KlB = &Kl[0][(size_t)w * 512];
  u16* VlB = &Vl[0][(size_t)w * 512];

  int qbase = myqt * 32;
  const u16* qp = Q + ((size_t)bh * SQ + qbase + j) * 64 + hi * 8;
  short8 qf[4];
#pragma unroll
  for (int kb = 0; kb < 4; ++kb) qf[kb] = *(const short8*)(qp + kb * 16);

  f32x16 o0, o1;
#pragma unroll
  for (int i = 0; i < 16; ++i) { o0[i] = 0.f; o1[i] = 0.f; }
  float mrun = -INFINITY, lrun = 0.f;

  gload_lds16(Kg0, KlB);
  gload_lds16(Kg0 + 2048, KlB + 2048);
  gload_lds16(Vg0, VlB);
  gload_lds16(Vg0 + 2048, VlB + 2048);
  __syncthreads();

  for (int ph = 0; ph < P; ++ph) {
    int cur = ph & 1;
    if (ph + 1 < P) {
      const u16* kg = Kg0 + (size_t)(2 * ph + 2) * 2048;
      const u16* vg = Vg0 + (size_t)(2 * ph + 2) * 2048;
      u16* kd = KlB + (cur ^ 1) * 4096;
      u16* vd = VlB + (cur ^ 1) * 4096;
      gload_lds16(kg, kd);
      gload_lds16(kg + 2048, kd + 2048);
      gload_lds16(vg, vd);
      gload_lds16(vg + 2048, vd + 2048);
    }

#pragma unroll
    for (int sub = 0; sub < 2; ++sub) {
      int kt = 2 * ph + sub;
      if (kt <= myqt) {
        const u16* Kc = &Kl[cur][sub * 2048];
        const u16* Vc = &Vl[cur][sub * 2048];

        short8 kcf[4];
#pragma unroll
        for (int kb = 0; kb < 4; ++kb)
          kcf[kb] = *(const short8*)&Kc[(hi + 2 * kb) * 256 + j * 8];

        f32x16 s;
#pragma unroll
        for (int i = 0; i < 16; ++i) s[i] = 0.f;
        __builtin_amdgcn_s_setprio(1);
#pragma unroll
        for (int kb = 0; kb < 4; ++kb)
          s = __builtin_amdgcn_mfma_f32_32x32x16_bf16(kcf[kb], qf[kb], s, 0, 0, 0);
        __builtin_amdgcn_s_setprio(0);

        short8 va0 = *(const short8*)&Vc[hi * 512 + j * 8];
        short8 va1 = *(const short8*)&Vc[(hi + 2) * 512 + j * 8];
        short8 vb0 = *(const short8*)&Vc[hi * 512 + (j + 32) * 8];
        short8 vb1 = *(const short8*)&Vc[(hi + 2) * 512 + (j + 32) * 8];

        if (!((mb >> kt) & 1ull)) {
#pragma unroll
          for (int rq = 0; rq < 4; ++rq) {
            int4 mv = *(const int4*)(mp + kt * 32 + 8 * rq);
            if (!mv.x) s[4 * rq + 0] = -INFINITY;
            if (!mv.y) s[4 * rq + 1] = -INFINITY;
            if (!mv.z) s[4 * rq + 2] = -INFINITY;
            if (!mv.w) s[4 * rq + 3] = -INFINITY;
          }
        }
        if (kt == myqt) {
#pragma unroll
          for (int rq = 0; rq < 4; ++rq)
#pragma unroll
            for (int t = 0; t < 4; ++t)
              if (8 * rq + 4 * hi + t > j) s[4 * rq + t] = -INFINITY;
        }

        float t0 = fmaxf(fmaxf(fmaxf(s[0], s[1]), fmaxf(s[2], s[3])),
                         fmaxf(fmaxf(s[4], s[5]), fmaxf(s[6], s[7])));
        t0 = fmaxf(t0, fmaxf(fmaxf(fmaxf(s[8], s[9]), fmaxf(s[10], s[11])),
                             fmaxf(fmaxf(s[12], s[13]), fmaxf(s[14], s[15]))));
        if (!__all(t0 <= mrun + 8.0f)) {
          float tm2 = xmax32(t0);
          float mn = fmaxf(fmaxf(mrun, tm2), -1e30f);
          float alpha = fexp2(mrun - mn);
          mrun = mn;
          lrun *= alpha;
#pragma unroll
          for (int i = 0; i < 16; ++i) { o0[i] *= alpha; o1[i] *= alpha; }
        }
        float ts = 0.f;
#pragma unroll
        for (int i = 0; i < 16; ++i) {
          float pv = fexp2(s[i] - mrun);
          s[i] = pv;
          ts += pv;
        }
        lrun += ts;

        u32 pa[4], pb[4];
#pragma unroll
        for (int q2 = 0; q2 < 4; ++q2) {
          pa[q2] = pkbf(s[4 * q2 + 0], s[4 * q2 + 1]);
          pb[q2] = pkbf(s[4 * q2 + 2], s[4 * q2 + 3]);
        }
        u32 ya01 = xword(hi ? pa[0] : pa[1]);
        u32 yb01 = xword(hi ? pb[0] : pb[1]);
        u32 ya23 = xword(hi ? pa[2] : pa[3]);
        u32 yb23 = xword(hi ? pb[2] : pb[3]);
        union { short8 s8; u32 wd[4]; } f0, f1;
        f0.wd[0] = hi ? ya01 : pa[0];
        f0.wd[1] = hi ? yb01 : pb[0];
        f0.wd[2] = hi ? pa[1] : ya01;
        f0.wd[3] = hi ? pb[1] : yb01;
        f1.wd[0] = hi ? ya23 : pa[2];
        f1.wd[1] = hi ? yb23 : pb[2];
        f1.wd[2] = hi ? pa[3] : ya23;
        f1.wd[3] = hi ? pb[3] : yb23;

        __builtin_amdgcn_s_setprio(1);
        o0 = __builtin_amdgcn_mfma_f32_32x32x16_bf16(va0, f0.s8, o0, 0, 0, 0);
        o0 = __builtin_amdgcn_mfma_f32_32x32x16_bf16(va1, f1.s8, o0, 0, 0, 0);
        o1 = __builtin_amdgcn_mfma_f32_32x32x16_bf16(vb0, f0.s8, o1, 0, 0, 0);
        o1 = __builtin_amdgcn_mfma_f32_32x32x16_bf16(vb1, f1.s8, o1, 0, 0, 0);
        __builtin_amdgcn_s_setprio(0);
      }
    }

    __syncthreads();
  }

  float lfull = xsum32(lrun);
  float inv = 1.0f / lfull;
  u16* ob = O + ((size_t)b * SQ + qbase + j) * DQ + h * 64 + 4 * hi;
#pragma unroll
  for (int q2 = 0; q2 < 4; ++q2) {
#pragma unroll
    for (int e = 0; e < 2; ++e) {
      *(u32*)(ob + 8 * q2 + 2 * e) = pkbf(o0[4 * q2 + 2 * e] * inv, o0[4 * q2 + 2 * e + 1] * inv);
      *(u32*)(ob + 32 + 8 * q2 + 2 * e) = pkbf(o1[4 * q2 + 2 * e] * inv, o1[4 * q2 + 2 * e + 1] * inv);
    }
  }
}

extern "C" void kernel_launch(void* const* d_in, const int* in_sizes, int n_in,
                              void* d_out, int out_size, void* d_ws, size_t ws_size,
                              hipStream_t stream) {
  const float* x = (const float*)d_in[0];
  const int* mask = (const int*)d_in[1];
  const float* wqkv = (const float*)d_in[2];
  const float* wout = (const float*)d_in[3];
  float* out = (float*)d_out;
  char* ws = (char*)d_ws;

  u16* xb    = (u16*)(ws + 0);           // 16 MB linear [8192][1024]
  u16* wqkvT = (u16*)(ws + 16777216);    // 6 MB  [3072][1024]
  u16* woutT = (u16*)(ws + 23068672);    // 2 MB  [1024][1024]
  u16* qbuf  = (u16*)(ws + 25165824);    // 16 MB [bh][S][64]
  u16* kbuf  = (u16*)(ws + 41943040);    // 16 MB [bh][64 kt][8 slot][32 j][8] tiled
  u16* vTs   = (u16*)(ws + 75497472);    // 16 MB [bh][64 kt][4 slot][64 d][8] tiled
  u16* attnb = (u16*)(ws + 92274688);    // 16 MB [B*S][1024]
  float* tab = (float*)(ws + 109051904); // 512 KB
  u64* mbits = (u64*)(ws + 109576192);   // 32 B

  k_prep<<<12545, 256, 0, stream>>>(x, xb, wqkv, wqkvT, wout, woutT, tab, mask, mbits);
  k_gemm8<<<256, 512, 0, stream>>>(xb, wqkvT, qbuf, kbuf, tab);
  k_gemm<1><<<512, 256, 0, stream>>>(xb, wqkvT, nullptr, vTs, 1024, 16);
  k_flash12<<<1024, 256, 0, stream>>>(qbuf, kbuf, vTs, mask, mbits, attnb);
  k_gemm<0><<<512, 256, 0, stream>>>(attnb, woutT, out, nullptr, 1024, 0);
}

// Round 19
// 185.803 us; speedup vs baseline: 1.0195x; 1.0195x over previous
//
#include <hip/hip_runtime.h>

#define BQ 4
#define SQ 2048
#define DQ 1024
#define HQ 16
#define BHQ 64

typedef __attribute__((ext_vector_type(8))) short short8;
typedef __attribute__((ext_vector_type(4))) float f32x4;
typedef __attribute__((ext_vector_type(16))) float f32x16;
typedef __attribute__((ext_vector_type(2))) unsigned int u32x2;
typedef unsigned short u16;
typedef unsigned int u32;
typedef unsigned long long u64;

__device__ __forceinline__ u16 f2bf(float f) {
  u32 u = __float_as_uint(f);
  u32 r = u + 0x7fffu + ((u >> 16) & 1u);
  return (u16)(r >> 16);
}
__device__ __forceinline__ float bf2f(u16 h) {
  return __uint_as_float(((u32)h) << 16);
}

// packed f32x2 -> bf16x2 (RNE), one instruction
__device__ __forceinline__ u32 pkbf(float lo, float hi_) {
  u32 r;
  asm("v_cvt_pk_bf16_f32 %0, %1, %2" : "=v"(r) : "v"(lo), "v"(hi_));
  return r;
}
// raw v_exp_f32: computes 2^x (input already in log2 domain)
__device__ __forceinline__ float fexp2(float x) {
  float r;
  asm("v_exp_f32 %0, %1" : "=v"(r) : "v"(x));
  return r;
}
// cross-half exchange via shfl (known-correct)
__device__ __forceinline__ float xmax32(float x) { return fmaxf(x, __shfl_xor(x, 32)); }
__device__ __forceinline__ float xsum32(float x) { return x + __shfl_xor(x, 32); }
__device__ __forceinline__ u32 xword(u32 send) { return (u32)__shfl_xor((int)send, 32); }

// async global->LDS, 16B per lane. LDS dest must be wave-uniform; HW adds lane*16.
__device__ __forceinline__ void gload_lds16(const void* g, void* l) {
  __builtin_amdgcn_global_load_lds(
      (const __attribute__((address_space(1))) u32*)(unsigned long long)g,
      (__attribute__((address_space(3))) u32*)(u32)(unsigned long long)l,
      16, 0, 0);
}

// ---------------- fused prep: cvt x | transpose wqkv | transpose wout | rope tab | mflags ----------------
__device__ __forceinline__ void transpose_body(const float* __restrict__ in, u16* __restrict__ out,
                                               int R, int C, int bx, int by, int tid) {
  __shared__ float t[32][33];
  int c0 = bx * 32, r0 = by * 32;
  int tx = tid & 31, ty = tid >> 5;
  for (int rr = ty; rr < 32; rr += 8)
    t[rr][tx] = in[(size_t)(r0 + rr) * C + c0 + tx];
  __syncthreads();
  for (int rr = ty; rr < 32; rr += 8)
    out[(size_t)(c0 + rr) * R + r0 + tx] = f2bf(t[tx][rr]);
}

__global__ __launch_bounds__(256) void k_prep(const float* __restrict__ x, u16* __restrict__ xb,
                                              const float* __restrict__ wqkv, u16* __restrict__ wqkvT,
                                              const float* __restrict__ wout, u16* __restrict__ woutT,
                                              float* __restrict__ tab, const int* __restrict__ mask,
                                              u64* __restrict__ mbits) {
  int bid = blockIdx.x, tid = threadIdx.x;
  if (bid < 8192) {                       // cvt x -> bf16 (2M float4)
    int i = bid * 256 + tid;
    float4 v = ((const float4*)x)[i];
    ushort4 o;
    o.x = f2bf(v.x); o.y = f2bf(v.y); o.z = f2bf(v.z); o.w = f2bf(v.w);
    ((ushort4*)xb)[i] = o;
  } else if (bid < 11264) {               // transpose wqkv [1024][3072] -> [3072][1024]
    int t = bid - 8192;
    transpose_body(wqkv, wqkvT, 1024, 3072, t % 96, t / 96, tid);
  } else if (bid < 12288) {               // transpose wout [1024][1024]
    int t = bid - 11264;
    transpose_body(wout, woutT, 1024, 1024, t % 32, t / 32, tid);
  } else if (bid < 12544) {               // rope cos/sin table [S][32][2]
    int i = (bid - 12288) * 256 + tid;
    int s = i >> 5, dp = i & 31;
    float invf = expf(-0.28782313662425576f * (float)dp);
    float ang = (float)s * invf;
    tab[i * 2] = cosf(ang);
    tab[i * 2 + 1] = sinf(ang);
  } else {                                // mask bitmask (1 block: wave=batch, lane=chunk)
    int b = tid >> 6, c = tid & 63;
    int all1 = 1;
    for (int i = 0; i < 32; ++i) all1 &= (mask[b * SQ + c * 32 + i] != 0) ? 1 : 0;
    u64 m = __ballot(all1);
    if (c == 0) mbits[b] = m;
  }
}

// ---------------- GEMM: C[M,N] = A[M,K](bf16) @ Bt[N,K]^T(bf16) ----------------
// BK=64, K-swizzled LDS. 1D grid with XCD-chunked (tm,tn) map: xcd=bid&7 owns
// tm in [xcd*8, xcd*8+8) (2MB of A = L2-resident) across all tn epochs.
// EPI 0: write f32 C row-major. EPI 1 (QKV): fused RoPE q/k + tiled K/V scatter:
//   kbuf tiled [bh][kt][8 slot=d>>3][32 j=s&31][8 e]   (bank-optimal flash reads)
//   vTs  tiled [bh][kt][4 slot=k>>3][64 d][8 e]
template <int EPI>
__global__ __launch_bounds__(256) void k_gemm(const u16* __restrict__ A, const u16* __restrict__ Bt,
                                              float* __restrict__ Cf, u16* __restrict__ qb,
                                              u16* __restrict__ kb, u16* __restrict__ vTs,
                                              const float* __restrict__ tab, int K) {
  __shared__ u16 lA[128 * 64];
  __shared__ u16 lB[128 * 64];
  int bid = blockIdx.x;
  int i_ = bid >> 3;
  int tm = (bid & 7) * 8 + (i_ & 7);
  int tn = i_ >> 3;
  int tid = threadIdx.x, w = tid >> 6, l = tid & 63;
  int wm = w >> 1, wn = w & 1;
  int li = l & 15, lg = l >> 4;
  const u16* gA = A + (size_t)tm * 128 * K;
  const u16* gB = Bt + (size_t)tn * 128 * K;
  f32x4 acc[4][4];
#pragma unroll
  for (int i = 0; i < 4; i++)
#pragma unroll
    for (int j = 0; j < 4; j++) acc[i][j] = (f32x4){0.f, 0.f, 0.f, 0.f};

  int lr = l >> 3, lslot = l & 7;
  int scol = ((lslot ^ lr) * 8);

  for (int kt = 0; kt < K; kt += 64) {
    __syncthreads();
#pragma unroll
    for (int i = 0; i < 4; ++i) {
      int ch = i * 4 + w;
      int row = ch * 8 + lr;
      gload_lds16(gA + (size_t)row * K + kt + scol, &lA[ch * 512]);
      gload_lds16(gB + (size_t)row * K + kt + scol, &lB[ch * 512]);
    }
    __syncthreads();
#pragma unroll
    for (int kk = 0; kk < 2; ++kk) {
      short8 af[4], bfr[4];
#pragma unroll
      for (int mf = 0; mf < 4; ++mf) {
        int row = wm * 64 + mf * 16 + li;
        af[mf] = *(const short8*)&lA[row * 64 + (((kk * 4 + lg)) ^ (row & 7)) * 8];
      }
#pragma unroll
      for (int nf = 0; nf < 4; ++nf) {
        int row = wn * 64 + nf * 16 + li;
        bfr[nf] = *(const short8*)&lB[row * 64 + (((kk * 4 + lg)) ^ (row & 7)) * 8];
      }
#pragma unroll
      for (int mf = 0; mf < 4; ++mf)
#pragma unroll
        for (int nf = 0; nf < 4; ++nf)
          acc[mf][nf] = __builtin_amdgcn_mfma_f32_16x16x32_bf16(af[mf], bfr[nf], acc[mf][nf], 0, 0, 0);
    }
  }
  if (EPI == 0) {
#pragma unroll
    for (int mf = 0; mf < 4; ++mf) {
      int mg0 = tm * 128 + wm * 64 + mf * 16 + lg * 4;
#pragma unroll
      for (int nf = 0; nf < 4; ++nf) {
        int ng = tn * 128 + wn * 64 + nf * 16 + li;
#pragma unroll
        for (int r = 0; r < 4; ++r)
          Cf[(size_t)(mg0 + r) * 1024 + ng] = acc[mf][nf][r];
      }
    }
  } else {
    int which = tn >> 3;                 // 0=q 1=k 2=v (128-col tiles, 8 per matrix)
    int h = (tn & 7) * 2 + wn;           // head
    int b = tm >> 4;                     // 128 | 2048: block never straddles batches
    if (which < 2) {
      float scale = (which == 0) ? 0.125f * 1.44269504088896f : 1.0f;
      u16* qk0 = qb + (((size_t)b * HQ + h) * SQ << 6);
      u16* kb0 = kb + ((size_t)b * HQ + h) * (64 * 2048);
#pragma unroll
      for (int mf = 0; mf < 4; ++mf) {
#pragma unroll
        for (int r = 0; r < 4; ++r) {
          int s = (tm * 128 + wm * 64 + mf * 16 + lg * 4 + r) & 2047;
#pragma unroll
          for (int nf2 = 0; nf2 < 2; ++nf2) {
            int dp = nf2 * 16 + li;      // 0..31; rope pair (dp, dp+32)
            float2 cs = *(const float2*)&tab[(s * 32 + dp) * 2];
            float a = acc[mf][nf2][r];
            float bb = acc[mf][nf2 + 2][r];
            float lo = (a * cs.x - bb * cs.y) * scale;
            float hi2 = (bb * cs.x + a * cs.y) * scale;
            if (which == 0) {
              u16* dst = qk0 + ((size_t)s << 6);
              dst[dp] = f2bf(lo);
              dst[dp + 32] = f2bf(hi2);
            } else {
              // tiled K: [kt][slot=d>>3][j=s&31][e=d&7]
              u16* dst = kb0 + (s >> 5) * 2048 + (s & 31) * 8;
              dst[(dp >> 3) * 256 + (dp & 7)] = f2bf(lo);
              dst[(dp >> 3) * 256 + 1024 + (dp & 7)] = f2bf(hi2);  // d+32 -> slot+4
            }
          }
        }
      }
    } else {
      // tiled V: [kt][slot=k>>3][d][e=k&7]; pack 4 consecutive kk -> one 8B store
#pragma unroll
      for (int mf = 0; mf < 4; ++mf) {
        int s0 = (tm * 128 + wm * 64 + mf * 16 + lg * 4) & 2047;
        int kt = s0 >> 5, kk0 = s0 & 31;
        size_t tb = (((size_t)(b * HQ + h) * 64 + kt) * 2048) + (kk0 >> 3) * 512 + (kk0 & 7);
#pragma unroll
        for (int nf = 0; nf < 4; ++nf) {
          int d = nf * 16 + li;
          u32 w0 = pkbf(acc[mf][nf][0], acc[mf][nf][1]);
          u32 w1 = pkbf(acc[mf][nf][2], acc[mf][nf][3]);
          *(u32x2*)&vTs[tb + d * 8] = (u32x2){w0, w1};
        }
      }
    }
  }
}

// ---------------- flash v12 (80.7us verified): 2 k-tiles per barrier phase ----------------
// Same 1024-block grid / qsup quads / tiled bank-optimal LDS as the verified flash7.
// Per phase: stage 2 K-tiles + 2 V-tiles (16KB) into the other buffer, then run the
// per-tile body verbatim for sub-tiles 2ph and 2ph+1 (bit-identical math),
// ONE barrier per phase.
__global__ __launch_bounds__(256) void k_flash12(const u16* __restrict__ Q, const u16* __restrict__ Kb,
                                                 const u16* __restrict__ VTs, const int* __restrict__ mask,
                                                 const u64* __restrict__ mbits, u16* __restrict__ O) {
  __shared__ alignas(16) u16 Kl[2][4096];
  __shared__ alignas(16) u16 Vl[2][4096];
  int bid = blockIdx.x;
  int bh = bid & 63;
  int u = bid >> 6, v = u & 3, k4 = u >> 2;
  int qsup = (k4 == 0) ? v : (k4 == 1) ? 7 - v : (k4 == 2) ? 8 + v : 15 - v;
  int tid = threadIdx.x, w = tid >> 6, l = tid & 63;
  int j = l & 31, hi = l >> 5;
  int myqt = qsup * 4 + w;
  int P = 2 * qsup + 2;  // phases; tiles 0..4qsup+3
  int b = bh >> 4, h = bh & 15;
  const int* mp = mask + b * SQ + 4 * hi;
  u64 mb = mbits[b];

  const u16* Kg0 = Kb + (size_t)bh * (64 * 2048) + tid * 8;   // + kt*2048
  const u16* Vg0 = VTs + (size_t)bh * (64 * 2048) + tid * 8;  // + kt*2048
  u16* KlB = &Kl[0][(size_t)w * 512];  // wave-uniform dest bases (+sub*2048, +buf*4096 u16)
  u16* VlB = &Vl[0][(size_t)w * 512];

  int qbase = myqt * 32;
  const u16* qp = Q + ((size_t)bh * SQ + qbase + j) * 64 + hi * 8;
  short8 qf[4];
#pragma unroll
  for (int kb = 0; kb < 4; ++kb) qf[kb] = *(const short8*)(qp + kb * 16);

  f32x16 o0, o1;
#pragma unroll
  for (int i = 0; i < 16; ++i) { o0[i] = 0.f; o1[i] = 0.f; }
  float mrun = -INFINITY, lrun = 0.f;

  // prologue: stage tiles 0,1 into buffer 0
  gload_lds16(Kg0, KlB);
  gload_lds16(Kg0 + 2048, KlB + 2048);
  gload_lds16(Vg0, VlB);
  gload_lds16(Vg0 + 2048, VlB + 2048);
  __syncthreads();

  for (int ph = 0; ph < P; ++ph) {
    int cur = ph & 1;
    if (ph + 1 < P) {  // stage next 2 tiles into other buffer
      const u16* kg = Kg0 + (size_t)(2 * ph + 2) * 2048;
      const u16* vg = Vg0 + (size_t)(2 * ph + 2) * 2048;
      u16* kd = KlB + (cur ^ 1) * 4096;
      u16* vd = VlB + (cur ^ 1) * 4096;
      gload_lds16(kg, kd);
      gload_lds16(kg + 2048, kd + 2048);
      gload_lds16(vg, vd);
      gload_lds16(vg + 2048, vd + 2048);
    }

#pragma unroll
    for (int sub = 0; sub < 2; ++sub) {
      int kt = 2 * ph + sub;
      if (kt <= myqt) {
        const u16* Kc = &Kl[cur][sub * 2048];
        const u16* Vc = &Vl[cur][sub * 2048];

        // K fragment: tiled [slot=hi+2kb][j][8] -> consecutive 16B across lanes
        short8 kcf[4];
#pragma unroll
        for (int kb = 0; kb < 4; ++kb)
          kcf[kb] = *(const short8*)&Kc[(hi + 2 * kb) * 256 + j * 8];

        f32x16 s;
#pragma unroll
        for (int i = 0; i < 16; ++i) s[i] = 0.f;
        __builtin_amdgcn_s_setprio(1);
#pragma unroll
        for (int kb = 0; kb < 4; ++kb)
          s = __builtin_amdgcn_mfma_f32_32x32x16_bf16(kcf[kb], qf[kb], s, 0, 0, 0);
        __builtin_amdgcn_s_setprio(0);

        // V fragments: tiled [slot][d][8]
        short8 va0 = *(const short8*)&Vc[hi * 512 + j * 8];
        short8 va1 = *(const short8*)&Vc[(hi + 2) * 512 + j * 8];
        short8 vb0 = *(const short8*)&Vc[hi * 512 + (j + 32) * 8];
        short8 vb1 = *(const short8*)&Vc[(hi + 2) * 512 + (j + 32) * 8];

        // pad mask: only when this 32-chunk has zeros (never in this harness)
        if (!((mb >> kt) & 1ull)) {
#pragma unroll
          for (int rq = 0; rq < 4; ++rq) {
            int4 mv = *(const int4*)(mp + kt * 32 + 8 * rq);
            if (!mv.x) s[4 * rq + 0] = -INFINITY;
            if (!mv.y) s[4 * rq + 1] = -INFINITY;
            if (!mv.z) s[4 * rq + 2] = -INFINITY;
            if (!mv.w) s[4 * rq + 3] = -INFINITY;
          }
        }
        // causal: diagonal tile masks k>q
        if (kt == myqt) {
#pragma unroll
          for (int rq = 0; rq < 4; ++rq)
#pragma unroll
            for (int t = 0; t < 4; ++t)
              if (8 * rq + 4 * hi + t > j) s[4 * rq + t] = -INFINITY;
        }

        // online softmax in log2 domain, fully in-register
        float t0 = fmaxf(fmaxf(fmaxf(s[0], s[1]), fmaxf(s[2], s[3])),
                         fmaxf(fmaxf(s[4], s[5]), fmaxf(s[6], s[7])));
        t0 = fmaxf(t0, fmaxf(fmaxf(fmaxf(s[8], s[9]), fmaxf(s[10], s[11])),
                             fmaxf(fmaxf(s[12], s[13]), fmaxf(s[14], s[15]))));
        if (!__all(t0 <= mrun + 8.0f)) {  // defer-max (T13)
          float tm2 = xmax32(t0);
          float mn = fmaxf(fmaxf(mrun, tm2), -1e30f);
          float alpha = fexp2(mrun - mn);
          mrun = mn;
          lrun *= alpha;
#pragma unroll
          for (int i = 0; i < 16; ++i) { o0[i] *= alpha; o1[i] *= alpha; }
        }
        float ts = 0.f;
#pragma unroll
        for (int i = 0; i < 16; ++i) {
          float pv = fexp2(s[i] - mrun);
          s[i] = pv;
          ts += pv;
        }
        lrun += ts;

        // pack P^T into B fragments: cvt_pk pairs + one cross-half shfl per word-pair
        u32 pa[4], pb[4];
#pragma unroll
        for (int q2 = 0; q2 < 4; ++q2) {
          pa[q2] = pkbf(s[4 * q2 + 0], s[4 * q2 + 1]);
          pb[q2] = pkbf(s[4 * q2 + 2], s[4 * q2 + 3]);
        }
        u32 ya01 = xword(hi ? pa[0] : pa[1]);
        u32 yb01 = xword(hi ? pb[0] : pb[1]);
        u32 ya23 = xword(hi ? pa[2] : pa[3]);
        u32 yb23 = xword(hi ? pb[2] : pb[3]);
        union { short8 s8; u32 wd[4]; } f0, f1;
        f0.wd[0] = hi ? ya01 : pa[0];
        f0.wd[1] = hi ? yb01 : pb[0];
        f0.wd[2] = hi ? pa[1] : ya01;
        f0.wd[3] = hi ? pb[1] : yb01;
        f1.wd[0] = hi ? ya23 : pa[2];
        f1.wd[1] = hi ? yb23 : pb[2];
        f1.wd[2] = hi ? pa[3] : ya23;
        f1.wd[3] = hi ? pb[3] : yb23;

        // PV: O^T += V^T(frag A) x P^T(frag B)
        __builtin_amdgcn_s_setprio(1);
        o0 = __builtin_amdgcn_mfma_f32_32x32x16_bf16(va0, f0.s8, o0, 0, 0, 0);
        o0 = __builtin_amdgcn_mfma_f32_32x32x16_bf16(va1, f1.s8, o0, 0, 0, 0);
        o1 = __builtin_amdgcn_mfma_f32_32x32x16_bf16(vb0, f0.s8, o1, 0, 0, 0);
        o1 = __builtin_amdgcn_mfma_f32_32x32x16_bf16(vb1, f1.s8, o1, 0, 0, 0);
        __builtin_amdgcn_s_setprio(0);
      }
    }

    __syncthreads();  // drains vmem (next stage) + all waves done reading cur
  }

  // epilogue: merge the two halves' lrun, store q rows
  float lfull = xsum32(lrun);
  float inv = 1.0f / lfull;
  u16* ob = O + ((size_t)b * SQ + qbase + j) * DQ + h * 64 + 4 * hi;
#pragma unroll
  for (int q2 = 0; q2 < 4; ++q2) {
#pragma unroll
    for (int e = 0; e < 2; ++e) {
      *(u32*)(ob + 8 * q2 + 2 * e) = pkbf(o0[4 * q2 + 2 * e] * inv, o0[4 * q2 + 2 * e + 1] * inv);
      *(u32*)(ob + 32 + 8 * q2 + 2 * e) = pkbf(o1[4 * q2 + 2 * e] * inv, o1[4 * q2 + 2 * e + 1] * inv);
    }
  }
}

extern "C" void kernel_launch(void* const* d_in, const int* in_sizes, int n_in,
                              void* d_out, int out_size, void* d_ws, size_t ws_size,
                              hipStream_t stream) {
  const float* x = (const float*)d_in[0];
  const int* mask = (const int*)d_in[1];
  const float* wqkv = (const float*)d_in[2];
  const float* wout = (const float*)d_in[3];
  float* out = (float*)d_out;
  char* ws = (char*)d_ws;

  u16* xb    = (u16*)(ws + 0);           // 16 MB
  u16* wqkvT = (u16*)(ws + 16777216);    // 6 MB  [3072][1024]
  u16* woutT = (u16*)(ws + 23068672);    // 2 MB  [1024][1024]
  u16* qbuf  = (u16*)(ws + 25165824);    // 16 MB [bh][S][64]
  u16* kbuf  = (u16*)(ws + 41943040);    // 16 MB [bh][64 kt][8 slot][32 j][8] tiled
  u16* vTs   = (u16*)(ws + 75497472);    // 16 MB [bh][64 kt][4 slot][64 d][8] tiled
  u16* attnb = (u16*)(ws + 92274688);    // 16 MB [B*S][1024]
  float* tab = (float*)(ws + 109051904); // 512 KB
  u64* mbits = (u64*)(ws + 109576192);   // 32 B

  k_prep<<<12545, 256, 0, stream>>>(x, xb, wqkv, wqkvT, wout, woutT, tab, mask, mbits);
  k_gemm<1><<<1536, 256, 0, stream>>>(xb, wqkvT, nullptr, qbuf, kbuf, vTs, tab, 1024);
  k_flash12<<<1024, 256, 0, stream>>>(qbuf, kbuf, vTs, mask, mbits, attnb);
  k_gemm<0><<<512, 256, 0, stream>>>(attnb, woutT, out, nullptr, nullptr, nullptr, nullptr, 1024);
}

// Round 20
// 183.521 us; speedup vs baseline: 1.0321x; 1.0124x over previous
//
#include <hip/hip_runtime.h>

#define BQ 4
#define SQ 2048
#define DQ 1024
#define HQ 16
#define BHQ 64

typedef __attribute__((ext_vector_type(8))) short short8;
typedef __attribute__((ext_vector_type(4))) float f32x4;
typedef __attribute__((ext_vector_type(16))) float f32x16;
typedef __attribute__((ext_vector_type(2))) unsigned int u32x2;
typedef unsigned short u16;
typedef unsigned int u32;
typedef unsigned long long u64;

__device__ __forceinline__ u16 f2bf(float f) {
  u32 u = __float_as_uint(f);
  u32 r = u + 0x7fffu + ((u >> 16) & 1u);
  return (u16)(r >> 16);
}
__device__ __forceinline__ float bf2f(u16 h) {
  return __uint_as_float(((u32)h) << 16);
}

// packed f32x2 -> bf16x2 (RNE), one instruction
__device__ __forceinline__ u32 pkbf(float lo, float hi_) {
  u32 r;
  asm("v_cvt_pk_bf16_f32 %0, %1, %2" : "=v"(r) : "v"(lo), "v"(hi_));
  return r;
}
// raw v_exp_f32: computes 2^x (input already in log2 domain)
__device__ __forceinline__ float fexp2(float x) {
  float r;
  asm("v_exp_f32 %0, %1" : "=v"(r) : "v"(x));
  return r;
}
// cross-half exchange via shfl (rare/epilogue paths only)
__device__ __forceinline__ float xmax32(float x) { return fmaxf(x, __shfl_xor(x, 32)); }
__device__ __forceinline__ float xsum32(float x) { return x + __shfl_xor(x, 32); }
// T12 primitive (m255: 1.20x vs ds_bpermute): exchange a's upper 32 lanes with b's
// lower 32 lanes. After call: a = [a.lo | b.lo], b = [a.hi | b.hi] (lane-wise).
__device__ __forceinline__ void pswap(u32& a, u32& b) {
  u32x2 r = __builtin_amdgcn_permlane32_swap(a, b, false, false);
  a = r.x;
  b = r.y;
}

// async global->LDS, 16B per lane. LDS dest must be wave-uniform; HW adds lane*16.
__device__ __forceinline__ void gload_lds16(const void* g, void* l) {
  __builtin_amdgcn_global_load_lds(
      (const __attribute__((address_space(1))) u32*)(unsigned long long)g,
      (__attribute__((address_space(3))) u32*)(u32)(unsigned long long)l,
      16, 0, 0);
}

// ---------------- fused prep: cvt x | transpose wqkv | transpose wout | rope tab | mflags ----------------
__device__ __forceinline__ void transpose_body(const float* __restrict__ in, u16* __restrict__ out,
                                               int R, int C, int bx, int by, int tid) {
  __shared__ float t[32][33];
  int c0 = bx * 32, r0 = by * 32;
  int tx = tid & 31, ty = tid >> 5;
  for (int rr = ty; rr < 32; rr += 8)
    t[rr][tx] = in[(size_t)(r0 + rr) * C + c0 + tx];
  __syncthreads();
  for (int rr = ty; rr < 32; rr += 8)
    out[(size_t)(c0 + rr) * R + r0 + tx] = f2bf(t[tx][rr]);
}

__global__ __launch_bounds__(256) void k_prep(const float* __restrict__ x, u16* __restrict__ xb,
                                              const float* __restrict__ wqkv, u16* __restrict__ wqkvT,
                                              const float* __restrict__ wout, u16* __restrict__ woutT,
                                              float* __restrict__ tab, const int* __restrict__ mask,
                                              u64* __restrict__ mbits) {
  int bid = blockIdx.x, tid = threadIdx.x;
  if (bid < 8192) {                       // cvt x -> bf16 (2M float4)
    int i = bid * 256 + tid;
    float4 v = ((const float4*)x)[i];
    ushort4 o;
    o.x = f2bf(v.x); o.y = f2bf(v.y); o.z = f2bf(v.z); o.w = f2bf(v.w);
    ((ushort4*)xb)[i] = o;
  } else if (bid < 11264) {               // transpose wqkv [1024][3072] -> [3072][1024]
    int t = bid - 8192;
    transpose_body(wqkv, wqkvT, 1024, 3072, t % 96, t / 96, tid);
  } else if (bid < 12288) {               // transpose wout [1024][1024]
    int t = bid - 11264;
    transpose_body(wout, woutT, 1024, 1024, t % 32, t / 32, tid);
  } else if (bid < 12544) {               // rope cos/sin table [S][32][2]
    int i = (bid - 12288) * 256 + tid;
    int s = i >> 5, dp = i & 31;
    float invf = expf(-0.28782313662425576f * (float)dp);
    float ang = (float)s * invf;
    tab[i * 2] = cosf(ang);
    tab[i * 2 + 1] = sinf(ang);
  } else {                                // mask bitmask (1 block: wave=batch, lane=chunk)
    int b = tid >> 6, c = tid & 63;
    int all1 = 1;
    for (int i = 0; i < 32; ++i) all1 &= (mask[b * SQ + c * 32 + i] != 0) ? 1 : 0;
    u64 m = __ballot(all1);
    if (c == 0) mbits[b] = m;
  }
}

// ---------------- GEMM: C[M,N] = A[M,K](bf16) @ Bt[N,K]^T(bf16) ----------------
// BK=64, K-swizzled LDS. 1D grid with XCD-chunked (tm,tn) map: xcd=bid&7 owns
// tm in [xcd*8, xcd*8+8) (2MB of A = L2-resident) across all tn epochs.
// EPI 0: write f32 C row-major. EPI 1 (QKV): fused RoPE q/k + tiled K/V scatter:
//   kbuf tiled [bh][kt][8 slot=d>>3][32 j=s&31][8 e]   (bank-optimal flash reads)
//   vTs  tiled [bh][kt][4 slot=k>>3][64 d][8 e]
template <int EPI>
__global__ __launch_bounds__(256) void k_gemm(const u16* __restrict__ A, const u16* __restrict__ Bt,
                                              float* __restrict__ Cf, u16* __restrict__ qb,
                                              u16* __restrict__ kb, u16* __restrict__ vTs,
                                              const float* __restrict__ tab, int K) {
  __shared__ u16 lA[128 * 64];
  __shared__ u16 lB[128 * 64];
  int bid = blockIdx.x;
  int i_ = bid >> 3;
  int tm = (bid & 7) * 8 + (i_ & 7);
  int tn = i_ >> 3;
  int tid = threadIdx.x, w = tid >> 6, l = tid & 63;
  int wm = w >> 1, wn = w & 1;
  int li = l & 15, lg = l >> 4;
  const u16* gA = A + (size_t)tm * 128 * K;
  const u16* gB = Bt + (size_t)tn * 128 * K;
  f32x4 acc[4][4];
#pragma unroll
  for (int i = 0; i < 4; i++)
#pragma unroll
    for (int j = 0; j < 4; j++) acc[i][j] = (f32x4){0.f, 0.f, 0.f, 0.f};

  int lr = l >> 3, lslot = l & 7;
  int scol = ((lslot ^ lr) * 8);

  for (int kt = 0; kt < K; kt += 64) {
    __syncthreads();
#pragma unroll
    for (int i = 0; i < 4; ++i) {
      int ch = i * 4 + w;
      int row = ch * 8 + lr;
      gload_lds16(gA + (size_t)row * K + kt + scol, &lA[ch * 512]);
      gload_lds16(gB + (size_t)row * K + kt + scol, &lB[ch * 512]);
    }
    __syncthreads();
#pragma unroll
    for (int kk = 0; kk < 2; ++kk) {
      short8 af[4], bfr[4];
#pragma unroll
      for (int mf = 0; mf < 4; ++mf) {
        int row = wm * 64 + mf * 16 + li;
        af[mf] = *(const short8*)&lA[row * 64 + (((kk * 4 + lg)) ^ (row & 7)) * 8];
      }
#pragma unroll
      for (int nf = 0; nf < 4; ++nf) {
        int row = wn * 64 + nf * 16 + li;
        bfr[nf] = *(const short8*)&lB[row * 64 + (((kk * 4 + lg)) ^ (row & 7)) * 8];
      }
#pragma unroll
      for (int mf = 0; mf < 4; ++mf)
#pragma unroll
        for (int nf = 0; nf < 4; ++nf)
          acc[mf][nf] = __builtin_amdgcn_mfma_f32_16x16x32_bf16(af[mf], bfr[nf], acc[mf][nf], 0, 0, 0);
    }
  }
  if (EPI == 0) {
#pragma unroll
    for (int mf = 0; mf < 4; ++mf) {
      int mg0 = tm * 128 + wm * 64 + mf * 16 + lg * 4;
#pragma unroll
      for (int nf = 0; nf < 4; ++nf) {
        int ng = tn * 128 + wn * 64 + nf * 16 + li;
#pragma unroll
        for (int r = 0; r < 4; ++r)
          Cf[(size_t)(mg0 + r) * 1024 + ng] = acc[mf][nf][r];
      }
    }
  } else {
    int which = tn >> 3;                 // 0=q 1=k 2=v (128-col tiles, 8 per matrix)
    int h = (tn & 7) * 2 + wn;           // head
    int b = tm >> 4;                     // 128 | 2048: block never straddles batches
    if (which < 2) {
      float scale = (which == 0) ? 0.125f * 1.44269504088896f : 1.0f;
      u16* qk0 = qb + (((size_t)b * HQ + h) * SQ << 6);
      u16* kb0 = kb + ((size_t)b * HQ + h) * (64 * 2048);
#pragma unroll
      for (int mf = 0; mf < 4; ++mf) {
#pragma unroll
        for (int r = 0; r < 4; ++r) {
          int s = (tm * 128 + wm * 64 + mf * 16 + lg * 4 + r) & 2047;
#pragma unroll
          for (int nf2 = 0; nf2 < 2; ++nf2) {
            int dp = nf2 * 16 + li;      // 0..31; rope pair (dp, dp+32)
            float2 cs = *(const float2*)&tab[(s * 32 + dp) * 2];
            float a = acc[mf][nf2][r];
            float bb = acc[mf][nf2 + 2][r];
            float lo = (a * cs.x - bb * cs.y) * scale;
            float hi2 = (bb * cs.x + a * cs.y) * scale;
            if (which == 0) {
              u16* dst = qk0 + ((size_t)s << 6);
              dst[dp] = f2bf(lo);
              dst[dp + 32] = f2bf(hi2);
            } else {
              // tiled K: [kt][slot=d>>3][j=s&31][e=d&7]
              u16* dst = kb0 + (s >> 5) * 2048 + (s & 31) * 8;
              dst[(dp >> 3) * 256 + (dp & 7)] = f2bf(lo);
              dst[(dp >> 3) * 256 + 1024 + (dp & 7)] = f2bf(hi2);  // d+32 -> slot+4
            }
          }
        }
      }
    } else {
      // tiled V: [kt][slot=k>>3][d][e=k&7]; pack 4 consecutive kk -> one 8B store
#pragma unroll
      for (int mf = 0; mf < 4; ++mf) {
        int s0 = (tm * 128 + wm * 64 + mf * 16 + lg * 4) & 2047;
        int kt = s0 >> 5, kk0 = s0 & 31;
        size_t tb = (((size_t)(b * HQ + h) * 64 + kt) * 2048) + (kk0 >> 3) * 512 + (kk0 & 7);
#pragma unroll
        for (int nf = 0; nf < 4; ++nf) {
          int d = nf * 16 + li;
          u32 w0 = pkbf(acc[mf][nf][0], acc[mf][nf][1]);
          u32 w1 = pkbf(acc[mf][nf][2], acc[mf][nf][3]);
          *(u32x2*)&vTs[tb + d * 8] = (u32x2){w0, w1};
        }
      }
    }
  }
}

// ---------------- flash v13: flash12 + permlane32_swap P-pack (T12) ----------------
// Identical to the verified flash12 except the P->B-fragment exchange: the 4
// ds_bpermute (shfl_xor 32) + 16 cndmask selects are replaced by 4 VALU-latency
// v_permlane32_swap_b32. Word-equivalence (derived & checked per hi half):
//   after pswap(pa[0],pa[1]): hi=0 lane {pa0=k(0,1), pa1=k(4,5)},
//                             hi=1 lane {pa0=k(8,9), pa1=k(12,13)}
// so f0 = {pa0, pb0, pa1, pb1} and f1 = {pa2, pb2, pa3, pb3} unconditionally —
// bit-identical fragment bytes to the previous network.
__global__ __launch_bounds__(256) void k_flash12(const u16* __restrict__ Q, const u16* __restrict__ Kb,
                                                 const u16* __restrict__ VTs, const int* __restrict__ mask,
                                                 const u64* __restrict__ mbits, u16* __restrict__ O) {
  __shared__ alignas(16) u16 Kl[2][4096];
  __shared__ alignas(16) u16 Vl[2][4096];
  int bid = blockIdx.x;
  int bh = bid & 63;
  int u = bid >> 6, v = u & 3, k4 = u >> 2;
  int qsup = (k4 == 0) ? v : (k4 == 1) ? 7 - v : (k4 == 2) ? 8 + v : 15 - v;
  int tid = threadIdx.x, w = tid >> 6, l = tid & 63;
  int j = l & 31, hi = l >> 5;
  int myqt = qsup * 4 + w;
  int P = 2 * qsup + 2;  // phases; tiles 0..4qsup+3
  int b = bh >> 4, h = bh & 15;
  const int* mp = mask + b * SQ + 4 * hi;
  u64 mb = mbits[b];

  const u16* Kg0 = Kb + (size_t)bh * (64 * 2048) + tid * 8;   // + kt*2048
  const u16* Vg0 = VTs + (size_t)bh * (64 * 2048) + tid * 8;  // + kt*2048
  u16* KlB = &Kl[0][(size_t)w * 512];  // wave-uniform dest bases (+sub*2048, +buf*4096 u16)
  u16* VlB = &Vl[0][(size_t)w * 512];

  int qbase = myqt * 32;
  const u16* qp = Q + ((size_t)bh * SQ + qbase + j) * 64 + hi * 8;
  short8 qf[4];
#pragma unroll
  for (int kb = 0; kb < 4; ++kb) qf[kb] = *(const short8*)(qp + kb * 16);

  f32x16 o0, o1;
#pragma unroll
  for (int i = 0; i < 16; ++i) { o0[i] = 0.f; o1[i] = 0.f; }
  float mrun = -INFINITY, lrun = 0.f;

  // prologue: stage tiles 0,1 into buffer 0
  gload_lds16(Kg0, KlB);
  gload_lds16(Kg0 + 2048, KlB + 2048);
  gload_lds16(Vg0, VlB);
  gload_lds16(Vg0 + 2048, VlB + 2048);
  __syncthreads();

  for (int ph = 0; ph < P; ++ph) {
    int cur = ph & 1;
    if (ph + 1 < P) {  // stage next 2 tiles into other buffer
      const u16* kg = Kg0 + (size_t)(2 * ph + 2) * 2048;
      const u16* vg = Vg0 + (size_t)(2 * ph + 2) * 2048;
      u16* kd = KlB + (cur ^ 1) * 4096;
      u16* vd = VlB + (cur ^ 1) * 4096;
      gload_lds16(kg, kd);
      gload_lds16(kg + 2048, kd + 2048);
      gload_lds16(vg, vd);
      gload_lds16(vg + 2048, vd + 2048);
    }

#pragma unroll
    for (int sub = 0; sub < 2; ++sub) {
      int kt = 2 * ph + sub;
      if (kt <= myqt) {
        const u16* Kc = &Kl[cur][sub * 2048];
        const u16* Vc = &Vl[cur][sub * 2048];

        // K fragment: tiled [slot=hi+2kb][j][8] -> consecutive 16B across lanes
        short8 kcf[4];
#pragma unroll
        for (int kb = 0; kb < 4; ++kb)
          kcf[kb] = *(const short8*)&Kc[(hi + 2 * kb) * 256 + j * 8];

        f32x16 s;
#pragma unroll
        for (int i = 0; i < 16; ++i) s[i] = 0.f;
        __builtin_amdgcn_s_setprio(1);
#pragma unroll
        for (int kb = 0; kb < 4; ++kb)
          s = __builtin_amdgcn_mfma_f32_32x32x16_bf16(kcf[kb], qf[kb], s, 0, 0, 0);
        __builtin_amdgcn_s_setprio(0);

        // V fragments: tiled [slot][d][8]
        short8 va0 = *(const short8*)&Vc[hi * 512 + j * 8];
        short8 va1 = *(const short8*)&Vc[(hi + 2) * 512 + j * 8];
        short8 vb0 = *(const short8*)&Vc[hi * 512 + (j + 32) * 8];
        short8 vb1 = *(const short8*)&Vc[(hi + 2) * 512 + (j + 32) * 8];

        // pad mask: only when this 32-chunk has zeros (never in this harness)
        if (!((mb >> kt) & 1ull)) {
#pragma unroll
          for (int rq = 0; rq < 4; ++rq) {
            int4 mv = *(const int4*)(mp + kt * 32 + 8 * rq);
            if (!mv.x) s[4 * rq + 0] = -INFINITY;
            if (!mv.y) s[4 * rq + 1] = -INFINITY;
            if (!mv.z) s[4 * rq + 2] = -INFINITY;
            if (!mv.w) s[4 * rq + 3] = -INFINITY;
          }
        }
        // causal: diagonal tile masks k>q
        if (kt == myqt) {
#pragma unroll
          for (int rq = 0; rq < 4; ++rq)
#pragma unroll
            for (int t = 0; t < 4; ++t)
              if (8 * rq + 4 * hi + t > j) s[4 * rq + t] = -INFINITY;
        }

        // online softmax in log2 domain, fully in-register
        float t0 = fmaxf(fmaxf(fmaxf(s[0], s[1]), fmaxf(s[2], s[3])),
                         fmaxf(fmaxf(s[4], s[5]), fmaxf(s[6], s[7])));
        t0 = fmaxf(t0, fmaxf(fmaxf(fmaxf(s[8], s[9]), fmaxf(s[10], s[11])),
                             fmaxf(fmaxf(s[12], s[13]), fmaxf(s[14], s[15]))));
        if (!__all(t0 <= mrun + 8.0f)) {  // defer-max (T13)
          float tm2 = xmax32(t0);
          float mn = fmaxf(fmaxf(mrun, tm2), -1e30f);
          float alpha = fexp2(mrun - mn);
          mrun = mn;
          lrun *= alpha;
#pragma unroll
          for (int i = 0; i < 16; ++i) { o0[i] *= alpha; o1[i] *= alpha; }
        }
        float ts = 0.f;
#pragma unroll
        for (int i = 0; i < 16; ++i) {
          float pv = fexp2(s[i] - mrun);
          s[i] = pv;
          ts += pv;
        }
        lrun += ts;

        // pack P^T into B fragments: cvt_pk pairs + permlane32_swap (T12, no selects)
        u32 pa[4], pb[4];
#pragma unroll
        for (int q2 = 0; q2 < 4; ++q2) {
          pa[q2] = pkbf(s[4 * q2 + 0], s[4 * q2 + 1]);
          pb[q2] = pkbf(s[4 * q2 + 2], s[4 * q2 + 3]);
        }
        pswap(pa[0], pa[1]);
        pswap(pb[0], pb[1]);
        pswap(pa[2], pa[3]);
        pswap(pb[2], pb[3]);
        union { short8 s8; u32 wd[4]; } f0, f1;
        f0.wd[0] = pa[0];
        f0.wd[1] = pb[0];
        f0.wd[2] = pa[1];
        f0.wd[3] = pb[1];
        f1.wd[0] = pa[2];
        f1.wd[1] = pb[2];
        f1.wd[2] = pa[3];
        f1.wd[3] = pb[3];

        // PV: O^T += V^T(frag A) x P^T(frag B)
        __builtin_amdgcn_s_setprio(1);
        o0 = __builtin_amdgcn_mfma_f32_32x32x16_bf16(va0, f0.s8, o0, 0, 0, 0);
        o0 = __builtin_amdgcn_mfma_f32_32x32x16_bf16(va1, f1.s8, o0, 0, 0, 0);
        o1 = __builtin_amdgcn_mfma_f32_32x32x16_bf16(vb0, f0.s8, o1, 0, 0, 0);
        o1 = __builtin_amdgcn_mfma_f32_32x32x16_bf16(vb1, f1.s8, o1, 0, 0, 0);
        __builtin_amdgcn_s_setprio(0);
      }
    }

    __syncthreads();  // drains vmem (next stage) + all waves done reading cur
  }

  // epilogue: merge the two halves' lrun, store q rows
  float lfull = xsum32(lrun);
  float inv = 1.0f / lfull;
  u16* ob = O + ((size_t)b * SQ + qbase + j) * DQ + h * 64 + 4 * hi;
#pragma unroll
  for (int q2 = 0; q2 < 4; ++q2) {
#pragma unroll
    for (int e = 0; e < 2; ++e) {
      *(u32*)(ob + 8 * q2 + 2 * e) = pkbf(o0[4 * q2 + 2 * e] * inv, o0[4 * q2 + 2 * e + 1] * inv);
      *(u32*)(ob + 32 + 8 * q2 + 2 * e) = pkbf(o1[4 * q2 + 2 * e] * inv, o1[4 * q2 + 2 * e + 1] * inv);
    }
  }
}

extern "C" void kernel_launch(void* const* d_in, const int* in_sizes, int n_in,
                              void* d_out, int out_size, void* d_ws, size_t ws_size,
                              hipStream_t stream) {
  const float* x = (const float*)d_in[0];
  const int* mask = (const int*)d_in[1];
  const float* wqkv = (const float*)d_in[2];
  const float* wout = (const float*)d_in[3];
  float* out = (float*)d_out;
  char* ws = (char*)d_ws;

  u16* xb    = (u16*)(ws + 0);           // 16 MB
  u16* wqkvT = (u16*)(ws + 16777216);    // 6 MB  [3072][1024]
  u16* woutT = (u16*)(ws + 23068672);    // 2 MB  [1024][1024]
  u16* qbuf  = (u16*)(ws + 25165824);    // 16 MB [bh][S][64]
  u16* kbuf  = (u16*)(ws + 41943040);    // 16 MB [bh][64 kt][8 slot][32 j][8] tiled
  u16* vTs   = (u16*)(ws + 75497472);    // 16 MB [bh][64 kt][4 slot][64 d][8] tiled
  u16* attnb = (u16*)(ws + 92274688);    // 16 MB [B*S][1024]
  float* tab = (float*)(ws + 109051904); // 512 KB
  u64* mbits = (u64*)(ws + 109576192);   // 32 B

  k_prep<<<12545, 256, 0, stream>>>(x, xb, wqkv, wqkvT, wout, woutT, tab, mask, mbits);
  k_gemm<1><<<1536, 256, 0, stream>>>(xb, wqkvT, nullptr, qbuf, kbuf, vTs, tab, 1024);
  k_flash12<<<1024, 256, 0, stream>>>(qbuf, kbuf, vTs, mask, mbits, attnb);
  k_gemm<0><<<512, 256, 0, stream>>>(attnb, woutT, out, nullptr, nullptr, nullptr, nullptr, 1024);
}

// Round 21
// 181.885 us; speedup vs baseline: 1.0414x; 1.0090x over previous
//
#include <hip/hip_runtime.h>

#define BQ 4
#define SQ 2048
#define DQ 1024
#define HQ 16
#define BHQ 64

typedef __attribute__((ext_vector_type(8))) short short8;
typedef __attribute__((ext_vector_type(4))) float f32x4;
typedef __attribute__((ext_vector_type(16))) float f32x16;
typedef __attribute__((ext_vector_type(2))) unsigned int u32x2;
typedef unsigned short u16;
typedef unsigned int u32;
typedef unsigned long long u64;

__device__ __forceinline__ u16 f2bf(float f) {
  u32 u = __float_as_uint(f);
  u32 r = u + 0x7fffu + ((u >> 16) & 1u);
  return (u16)(r >> 16);
}
__device__ __forceinline__ float bf2f(u16 h) {
  return __uint_as_float(((u32)h) << 16);
}

// packed f32x2 -> bf16x2 (RNE), one instruction
__device__ __forceinline__ u32 pkbf(float lo, float hi_) {
  u32 r;
  asm("v_cvt_pk_bf16_f32 %0, %1, %2" : "=v"(r) : "v"(lo), "v"(hi_));
  return r;
}
// raw v_exp_f32: computes 2^x (input already in log2 domain)
__device__ __forceinline__ float fexp2(float x) {
  float r;
  asm("v_exp_f32 %0, %1" : "=v"(r) : "v"(x));
  return r;
}
// cross-half exchange via shfl (rare/epilogue paths only)
__device__ __forceinline__ float xmax32(float x) { return fmaxf(x, __shfl_xor(x, 32)); }
__device__ __forceinline__ float xsum32(float x) { return x + __shfl_xor(x, 32); }
// T12 primitive (m255: 1.20x vs ds_bpermute): exchange a's upper 32 lanes with b's
// lower 32 lanes. After call: a = [a.lo | b.lo], b = [a.hi | b.hi] (lane-wise).
__device__ __forceinline__ void pswap(u32& a, u32& b) {
  u32x2 r = __builtin_amdgcn_permlane32_swap(a, b, false, false);
  a = r.x;
  b = r.y;
}

// async global->LDS, 16B per lane. LDS dest must be wave-uniform; HW adds lane*16.
__device__ __forceinline__ void gload_lds16(const void* g, void* l) {
  __builtin_amdgcn_global_load_lds(
      (const __attribute__((address_space(1))) u32*)(unsigned long long)g,
      (__attribute__((address_space(3))) u32*)(u32)(unsigned long long)l,
      16, 0, 0);
}

// ---------------- fused prep: cvt x | transpose wqkv | transpose wout | rope tab | mflags ----------------
__device__ __forceinline__ void transpose_body(const float* __restrict__ in, u16* __restrict__ out,
                                               int R, int C, int bx, int by, int tid) {
  __shared__ float t[32][33];
  int c0 = bx * 32, r0 = by * 32;
  int tx = tid & 31, ty = tid >> 5;
  for (int rr = ty; rr < 32; rr += 8)
    t[rr][tx] = in[(size_t)(r0 + rr) * C + c0 + tx];
  __syncthreads();
  for (int rr = ty; rr < 32; rr += 8)
    out[(size_t)(c0 + rr) * R + r0 + tx] = f2bf(t[tx][rr]);
}

__global__ __launch_bounds__(256) void k_prep(const float* __restrict__ x, u16* __restrict__ xb,
                                              const float* __restrict__ wqkv, u16* __restrict__ wqkvT,
                                              const float* __restrict__ wout, u16* __restrict__ woutT,
                                              float* __restrict__ tab, const int* __restrict__ mask,
                                              u64* __restrict__ mbits) {
  int bid = blockIdx.x, tid = threadIdx.x;
  if (bid < 8192) {                       // cvt x -> bf16 (2M float4)
    int i = bid * 256 + tid;
    float4 v = ((const float4*)x)[i];
    ushort4 o;
    o.x = f2bf(v.x); o.y = f2bf(v.y); o.z = f2bf(v.z); o.w = f2bf(v.w);
    ((ushort4*)xb)[i] = o;
  } else if (bid < 11264) {               // transpose wqkv [1024][3072] -> [3072][1024]
    int t = bid - 8192;
    transpose_body(wqkv, wqkvT, 1024, 3072, t % 96, t / 96, tid);
  } else if (bid < 12288) {               // transpose wout [1024][1024]
    int t = bid - 11264;
    transpose_body(wout, woutT, 1024, 1024, t % 32, t / 32, tid);
  } else if (bid < 12544) {               // rope cos/sin table [S][32][2]
    int i = (bid - 12288) * 256 + tid;
    int s = i >> 5, dp = i & 31;
    float invf = expf(-0.28782313662425576f * (float)dp);
    float ang = (float)s * invf;
    tab[i * 2] = cosf(ang);
    tab[i * 2 + 1] = sinf(ang);
  } else {                                // mask bitmask (1 block: wave=batch, lane=chunk)
    int b = tid >> 6, c = tid & 63;
    int all1 = 1;
    for (int i = 0; i < 32; ++i) all1 &= (mask[b * SQ + c * 32 + i] != 0) ? 1 : 0;
    u64 m = __ballot(all1);
    if (c == 0) mbits[b] = m;
  }
}

// ---------------- GEMM: C[M,N] = A[M,K](bf16) @ Bt[N,K]^T(bf16) ----------------
// BK=64, K-swizzled LDS. 1D grid with XCD-chunked (tm,tn) map: xcd=bid&7 owns
// tm in [xcd*8, xcd*8+8) (2MB of A = L2-resident) across all tn epochs.
// EPI 0: write f32 C row-major. EPI 1 (QKV): fused RoPE q/k + tiled K/V scatter:
//   kbuf tiled [bh][kt][8 slot=d>>3][32 j=s&31][8 e]   (bank-optimal flash reads)
//   vTs  tiled [bh][kt][4 slot=k>>3][64 d][8 e]
template <int EPI>
__global__ __launch_bounds__(256) void k_gemm(const u16* __restrict__ A, const u16* __restrict__ Bt,
                                              float* __restrict__ Cf, u16* __restrict__ qb,
                                              u16* __restrict__ kb, u16* __restrict__ vTs,
                                              const float* __restrict__ tab, int K) {
  __shared__ u16 lA[128 * 64];
  __shared__ u16 lB[128 * 64];
  int bid = blockIdx.x;
  int i_ = bid >> 3;
  int tm = (bid & 7) * 8 + (i_ & 7);
  int tn = i_ >> 3;
  int tid = threadIdx.x, w = tid >> 6, l = tid & 63;
  int wm = w >> 1, wn = w & 1;
  int li = l & 15, lg = l >> 4;
  const u16* gA = A + (size_t)tm * 128 * K;
  const u16* gB = Bt + (size_t)tn * 128 * K;
  f32x4 acc[4][4];
#pragma unroll
  for (int i = 0; i < 4; i++)
#pragma unroll
    for (int j = 0; j < 4; j++) acc[i][j] = (f32x4){0.f, 0.f, 0.f, 0.f};

  int lr = l >> 3, lslot = l & 7;
  int scol = ((lslot ^ lr) * 8);

  for (int kt = 0; kt < K; kt += 64) {
    __syncthreads();
#pragma unroll
    for (int i = 0; i < 4; ++i) {
      int ch = i * 4 + w;
      int row = ch * 8 + lr;
      gload_lds16(gA + (size_t)row * K + kt + scol, &lA[ch * 512]);
      gload_lds16(gB + (size_t)row * K + kt + scol, &lB[ch * 512]);
    }
    __syncthreads();
#pragma unroll
    for (int kk = 0; kk < 2; ++kk) {
      short8 af[4], bfr[4];
#pragma unroll
      for (int mf = 0; mf < 4; ++mf) {
        int row = wm * 64 + mf * 16 + li;
        af[mf] = *(const short8*)&lA[row * 64 + (((kk * 4 + lg)) ^ (row & 7)) * 8];
      }
#pragma unroll
      for (int nf = 0; nf < 4; ++nf) {
        int row = wn * 64 + nf * 16 + li;
        bfr[nf] = *(const short8*)&lB[row * 64 + (((kk * 4 + lg)) ^ (row & 7)) * 8];
      }
#pragma unroll
      for (int mf = 0; mf < 4; ++mf)
#pragma unroll
        for (int nf = 0; nf < 4; ++nf)
          acc[mf][nf] = __builtin_amdgcn_mfma_f32_16x16x32_bf16(af[mf], bfr[nf], acc[mf][nf], 0, 0, 0);
    }
  }
  if (EPI == 0) {
#pragma unroll
    for (int mf = 0; mf < 4; ++mf) {
      int mg0 = tm * 128 + wm * 64 + mf * 16 + lg * 4;
#pragma unroll
      for (int nf = 0; nf < 4; ++nf) {
        int ng = tn * 128 + wn * 64 + nf * 16 + li;
#pragma unroll
        for (int r = 0; r < 4; ++r)
          Cf[(size_t)(mg0 + r) * 1024 + ng] = acc[mf][nf][r];
      }
    }
  } else {
    int which = tn >> 3;                 // 0=q 1=k 2=v (128-col tiles, 8 per matrix)
    int h = (tn & 7) * 2 + wn;           // head
    int b = tm >> 4;                     // 128 | 2048: block never straddles batches
    if (which < 2) {
      float scale = (which == 0) ? 0.125f * 1.44269504088896f : 1.0f;
      u16* qk0 = qb + (((size_t)b * HQ + h) * SQ << 6);
      u16* kb0 = kb + ((size_t)b * HQ + h) * (64 * 2048);
#pragma unroll
      for (int mf = 0; mf < 4; ++mf) {
#pragma unroll
        for (int r = 0; r < 4; ++r) {
          int s = (tm * 128 + wm * 64 + mf * 16 + lg * 4 + r) & 2047;
#pragma unroll
          for (int nf2 = 0; nf2 < 2; ++nf2) {
            int dp = nf2 * 16 + li;      // 0..31; rope pair (dp, dp+32)
            float2 cs = *(const float2*)&tab[(s * 32 + dp) * 2];
            float a = acc[mf][nf2][r];
            float bb = acc[mf][nf2 + 2][r];
            float lo = (a * cs.x - bb * cs.y) * scale;
            float hi2 = (bb * cs.x + a * cs.y) * scale;
            if (which == 0) {
              u16* dst = qk0 + ((size_t)s << 6);
              dst[dp] = f2bf(lo);
              dst[dp + 32] = f2bf(hi2);
            } else {
              // tiled K: [kt][slot=d>>3][j=s&31][e=d&7]
              u16* dst = kb0 + (s >> 5) * 2048 + (s & 31) * 8;
              dst[(dp >> 3) * 256 + (dp & 7)] = f2bf(lo);
              dst[(dp >> 3) * 256 + 1024 + (dp & 7)] = f2bf(hi2);  // d+32 -> slot+4
            }
          }
        }
      }
    } else {
      // tiled V: [kt][slot=k>>3][d][e=k&7]; pack 4 consecutive kk -> one 8B store
#pragma unroll
      for (int mf = 0; mf < 4; ++mf) {
        int s0 = (tm * 128 + wm * 64 + mf * 16 + lg * 4) & 2047;
        int kt = s0 >> 5, kk0 = s0 & 31;
        size_t tb = (((size_t)(b * HQ + h) * 64 + kt) * 2048) + (kk0 >> 3) * 512 + (kk0 & 7);
#pragma unroll
        for (int nf = 0; nf < 4; ++nf) {
          int d = nf * 16 + li;
          u32 w0 = pkbf(acc[mf][nf][0], acc[mf][nf][1]);
          u32 w1 = pkbf(acc[mf][nf][2], acc[mf][nf][3]);
          *(u32x2*)&vTs[tb + d * 8] = (u32x2){w0, w1};
        }
      }
    }
  }
}

// ---------------- flash v14: flash12 grid/staging + FUSED 2-sub-tile body ----------------
// Same 1024-block grid / qsup quads / tiled bank-optimal LDS / permlane pack as the
// verified round-20 kernel. Per phase the two sub-tiles are computed TOGETHER:
// two independent QK MFMA chains (2x ILP), one joint online-softmax over 64 keys
// (body verified in flash8), 8 PV MFMAs. One barrier per phase.
__global__ __launch_bounds__(256) void k_flash14(const u16* __restrict__ Q, const u16* __restrict__ Kb,
                                                 const u16* __restrict__ VTs, const int* __restrict__ mask,
                                                 const u64* __restrict__ mbits, u16* __restrict__ O) {
  __shared__ alignas(16) u16 Kl[2][4096];
  __shared__ alignas(16) u16 Vl[2][4096];
  int bid = blockIdx.x;
  int bh = bid & 63;
  int u = bid >> 6, v = u & 3, k4 = u >> 2;
  int qsup = (k4 == 0) ? v : (k4 == 1) ? 7 - v : (k4 == 2) ? 8 + v : 15 - v;
  int tid = threadIdx.x, w = tid >> 6, l = tid & 63;
  int j = l & 31, hi = l >> 5;
  int myqt = qsup * 4 + w;
  int P = 2 * qsup + 2;  // phases; tiles 0..4qsup+3
  int b = bh >> 4, h = bh & 15;
  const int* mp = mask + b * SQ + 4 * hi;
  u64 mb = mbits[b];

  const u16* Kg0 = Kb + (size_t)bh * (64 * 2048) + tid * 8;   // + kt*2048
  const u16* Vg0 = VTs + (size_t)bh * (64 * 2048) + tid * 8;  // + kt*2048
  u16* KlB = &Kl[0][(size_t)w * 512];  // wave-uniform dest bases (+sub*2048, +buf*4096 u16)
  u16* VlB = &Vl[0][(size_t)w * 512];

  int qbase = myqt * 32;
  const u16* qp = Q + ((size_t)bh * SQ + qbase + j) * 64 + hi * 8;
  short8 qf[4];
#pragma unroll
  for (int kb = 0; kb < 4; ++kb) qf[kb] = *(const short8*)(qp + kb * 16);

  f32x16 o0, o1;
#pragma unroll
  for (int i = 0; i < 16; ++i) { o0[i] = 0.f; o1[i] = 0.f; }
  float mrun = -INFINITY, lrun = 0.f;

  // prologue: stage tiles 0,1 into buffer 0
  gload_lds16(Kg0, KlB);
  gload_lds16(Kg0 + 2048, KlB + 2048);
  gload_lds16(Vg0, VlB);
  gload_lds16(Vg0 + 2048, VlB + 2048);
  __syncthreads();

  for (int ph = 0; ph < P; ++ph) {
    int cur = ph & 1;
    if (ph + 1 < P) {  // stage next 2 tiles into other buffer
      const u16* kg = Kg0 + (size_t)(2 * ph + 2) * 2048;
      const u16* vg = Vg0 + (size_t)(2 * ph + 2) * 2048;
      u16* kd = KlB + (cur ^ 1) * 4096;
      u16* vd = VlB + (cur ^ 1) * 4096;
      gload_lds16(kg, kd);
      gload_lds16(kg + 2048, kd + 2048);
      gload_lds16(vg, vd);
      gload_lds16(vg + 2048, vd + 2048);
    }

    int t0i = 2 * ph, t1i = 2 * ph + 1;
    if (t0i <= myqt) {
      const u16* Kc0 = &Kl[cur][0];
      const u16* Kc1 = &Kl[cur][2048];
      const u16* Vc0 = &Vl[cur][0];
      const u16* Vc1 = &Vl[cur][2048];

      // K fragments, both sub-tiles: tiled [slot=hi+2kb][j][8]
      short8 k0f[4], k1f[4];
#pragma unroll
      for (int kb = 0; kb < 4; ++kb) {
        k0f[kb] = *(const short8*)&Kc0[(hi + 2 * kb) * 256 + j * 8];
        k1f[kb] = *(const short8*)&Kc1[(hi + 2 * kb) * 256 + j * 8];
      }

      // two independent QK chains (2x MFMA ILP)
      f32x16 s0, s1;
#pragma unroll
      for (int i = 0; i < 16; ++i) { s0[i] = 0.f; s1[i] = 0.f; }
      __builtin_amdgcn_s_setprio(1);
#pragma unroll
      for (int kb = 0; kb < 4; ++kb) {
        s0 = __builtin_amdgcn_mfma_f32_32x32x16_bf16(k0f[kb], qf[kb], s0, 0, 0, 0);
        s1 = __builtin_amdgcn_mfma_f32_32x32x16_bf16(k1f[kb], qf[kb], s1, 0, 0, 0);
      }
      __builtin_amdgcn_s_setprio(0);

      // V fragments, both sub-tiles: tiled [slot][d][8]
      short8 va00 = *(const short8*)&Vc0[hi * 512 + j * 8];
      short8 va01 = *(const short8*)&Vc0[(hi + 2) * 512 + j * 8];
      short8 vb00 = *(const short8*)&Vc0[hi * 512 + (j + 32) * 8];
      short8 vb01 = *(const short8*)&Vc0[(hi + 2) * 512 + (j + 32) * 8];
      short8 va10 = *(const short8*)&Vc1[hi * 512 + j * 8];
      short8 va11 = *(const short8*)&Vc1[(hi + 2) * 512 + j * 8];
      short8 vb10 = *(const short8*)&Vc1[hi * 512 + (j + 32) * 8];
      short8 vb11 = *(const short8*)&Vc1[(hi + 2) * 512 + (j + 32) * 8];

      // pad mask per sub-tile (never taken in this harness)
      if (!((mb >> t0i) & 1ull)) {
#pragma unroll
        for (int rq = 0; rq < 4; ++rq) {
          int4 mv = *(const int4*)(mp + t0i * 32 + 8 * rq);
          if (!mv.x) s0[4 * rq + 0] = -INFINITY;
          if (!mv.y) s0[4 * rq + 1] = -INFINITY;
          if (!mv.z) s0[4 * rq + 2] = -INFINITY;
          if (!mv.w) s0[4 * rq + 3] = -INFINITY;
        }
      }
      if (!((mb >> t1i) & 1ull)) {
#pragma unroll
        for (int rq = 0; rq < 4; ++rq) {
          int4 mv = *(const int4*)(mp + t1i * 32 + 8 * rq);
          if (!mv.x) s1[4 * rq + 0] = -INFINITY;
          if (!mv.y) s1[4 * rq + 1] = -INFINITY;
          if (!mv.z) s1[4 * rq + 2] = -INFINITY;
          if (!mv.w) s1[4 * rq + 3] = -INFINITY;
        }
      }
      // causal (verified in flash8): diagonal tile masks k>q; beyond-diagonal all -inf
      if (t0i == myqt) {
#pragma unroll
        for (int rq = 0; rq < 4; ++rq)
#pragma unroll
          for (int t = 0; t < 4; ++t)
            if (8 * rq + 4 * hi + t > j) s0[4 * rq + t] = -INFINITY;
      }
      if (t1i >= myqt) {
        if (t1i > myqt) {
#pragma unroll
          for (int i = 0; i < 16; ++i) s1[i] = -INFINITY;
        } else {
#pragma unroll
          for (int rq = 0; rq < 4; ++rq)
#pragma unroll
            for (int t = 0; t < 4; ++t)
              if (8 * rq + 4 * hi + t > j) s1[4 * rq + t] = -INFINITY;
        }
      }

      // joint online softmax over 32 values (log2 domain) — flash8-verified
      float t0 = fmaxf(fmaxf(fmaxf(s0[0], s0[1]), fmaxf(s0[2], s0[3])),
                       fmaxf(fmaxf(s0[4], s0[5]), fmaxf(s0[6], s0[7])));
      t0 = fmaxf(t0, fmaxf(fmaxf(fmaxf(s0[8], s0[9]), fmaxf(s0[10], s0[11])),
                           fmaxf(fmaxf(s0[12], s0[13]), fmaxf(s0[14], s0[15]))));
      float t1 = fmaxf(fmaxf(fmaxf(s1[0], s1[1]), fmaxf(s1[2], s1[3])),
                       fmaxf(fmaxf(s1[4], s1[5]), fmaxf(s1[6], s1[7])));
      t1 = fmaxf(t1, fmaxf(fmaxf(fmaxf(s1[8], s1[9]), fmaxf(s1[10], s1[11])),
                           fmaxf(fmaxf(s1[12], s1[13]), fmaxf(s1[14], s1[15]))));
      float tmx = fmaxf(t0, t1);
      if (!__all(tmx <= mrun + 8.0f)) {  // defer-max (T13)
        float tm2 = xmax32(tmx);
        float mn = fmaxf(fmaxf(mrun, tm2), -1e30f);
        float alpha = fexp2(mrun - mn);
        mrun = mn;
        lrun *= alpha;
#pragma unroll
        for (int i = 0; i < 16; ++i) { o0[i] *= alpha; o1[i] *= alpha; }
      }
      float ts = 0.f;
#pragma unroll
      for (int i = 0; i < 16; ++i) {
        float pv = fexp2(s0[i] - mrun);
        s0[i] = pv;
        ts += pv;
      }
#pragma unroll
      for (int i = 0; i < 16; ++i) {
        float pv = fexp2(s1[i] - mrun);
        s1[i] = pv;
        ts += pv;
      }
      lrun += ts;

      // pack both P^T tiles: cvt_pk + permlane32_swap (T12, no selects)
      u32 pa[4], pb[4];
#pragma unroll
      for (int q2 = 0; q2 < 4; ++q2) {
        pa[q2] = pkbf(s0[4 * q2 + 0], s0[4 * q2 + 1]);
        pb[q2] = pkbf(s0[4 * q2 + 2], s0[4 * q2 + 3]);
      }
      pswap(pa[0], pa[1]);
      pswap(pb[0], pb[1]);
      pswap(pa[2], pa[3]);
      pswap(pb[2], pb[3]);
      union { short8 s8; u32 wd[4]; } f00, f01, f10, f11;
      f00.wd[0] = pa[0]; f00.wd[1] = pb[0]; f00.wd[2] = pa[1]; f00.wd[3] = pb[1];
      f01.wd[0] = pa[2]; f01.wd[1] = pb[2]; f01.wd[2] = pa[3]; f01.wd[3] = pb[3];
#pragma unroll
      for (int q2 = 0; q2 < 4; ++q2) {
        pa[q2] = pkbf(s1[4 * q2 + 0], s1[4 * q2 + 1]);
        pb[q2] = pkbf(s1[4 * q2 + 2], s1[4 * q2 + 3]);
      }
      pswap(pa[0], pa[1]);
      pswap(pb[0], pb[1]);
      pswap(pa[2], pa[3]);
      pswap(pb[2], pb[3]);
      f10.wd[0] = pa[0]; f10.wd[1] = pb[0]; f10.wd[2] = pa[1]; f10.wd[3] = pb[1];
      f11.wd[0] = pa[2]; f11.wd[1] = pb[2]; f11.wd[2] = pa[3]; f11.wd[3] = pb[3];

      // PV both sub-tiles: two independent chains per o-accumulator
      __builtin_amdgcn_s_setprio(1);
      o0 = __builtin_amdgcn_mfma_f32_32x32x16_bf16(va00, f00.s8, o0, 0, 0, 0);
      o1 = __builtin_amdgcn_mfma_f32_32x32x16_bf16(vb00, f00.s8, o1, 0, 0, 0);
      o0 = __builtin_amdgcn_mfma_f32_32x32x16_bf16(va01, f01.s8, o0, 0, 0, 0);
      o1 = __builtin_amdgcn_mfma_f32_32x32x16_bf16(vb01, f01.s8, o1, 0, 0, 0);
      o0 = __builtin_amdgcn_mfma_f32_32x32x16_bf16(va10, f10.s8, o0, 0, 0, 0);
      o1 = __builtin_amdgcn_mfma_f32_32x32x16_bf16(vb10, f10.s8, o1, 0, 0, 0);
      o0 = __builtin_amdgcn_mfma_f32_32x32x16_bf16(va11, f11.s8, o0, 0, 0, 0);
      o1 = __builtin_amdgcn_mfma_f32_32x32x16_bf16(vb11, f11.s8, o1, 0, 0, 0);
      __builtin_amdgcn_s_setprio(0);
    }

    __syncthreads();  // drains vmem (next stage) + all waves done reading cur
  }

  // epilogue: merge the two halves' lrun, store q rows
  float lfull = xsum32(lrun);
  float inv = 1.0f / lfull;
  u16* ob = O + ((size_t)b * SQ + qbase + j) * DQ + h * 64 + 4 * hi;
#pragma unroll
  for (int q2 = 0; q2 < 4; ++q2) {
#pragma unroll
    for (int e = 0; e < 2; ++e) {
      *(u32*)(ob + 8 * q2 + 2 * e) = pkbf(o0[4 * q2 + 2 * e] * inv, o0[4 * q2 + 2 * e + 1] * inv);
      *(u32*)(ob + 32 + 8 * q2 + 2 * e) = pkbf(o1[4 * q2 + 2 * e] * inv, o1[4 * q2 + 2 * e + 1] * inv);
    }
  }
}

extern "C" void kernel_launch(void* const* d_in, const int* in_sizes, int n_in,
                              void* d_out, int out_size, void* d_ws, size_t ws_size,
                              hipStream_t stream) {
  const float* x = (const float*)d_in[0];
  const int* mask = (const int*)d_in[1];
  const float* wqkv = (const float*)d_in[2];
  const float* wout = (const float*)d_in[3];
  float* out = (float*)d_out;
  char* ws = (char*)d_ws;

  u16* xb    = (u16*)(ws + 0);           // 16 MB
  u16* wqkvT = (u16*)(ws + 16777216);    // 6 MB  [3072][1024]
  u16* woutT = (u16*)(ws + 23068672);    // 2 MB  [1024][1024]
  u16* qbuf  = (u16*)(ws + 25165824);    // 16 MB [bh][S][64]
  u16* kbuf  = (u16*)(ws + 41943040);    // 16 MB [bh][64 kt][8 slot][32 j][8] tiled
  u16* vTs   = (u16*)(ws + 75497472);    // 16 MB [bh][64 kt][4 slot][64 d][8] tiled
  u16* attnb = (u16*)(ws + 92274688);    // 16 MB [B*S][1024]
  float* tab = (float*)(ws + 109051904); // 512 KB
  u64* mbits = (u64*)(ws + 109576192);   // 32 B

  k_prep<<<12545, 256, 0, stream>>>(x, xb, wqkv, wqkvT, wout, woutT, tab, mask, mbits);
  k_gemm<1><<<1536, 256, 0, stream>>>(xb, wqkvT, nullptr, qbuf, kbuf, vTs, tab, 1024);
  k_flash14<<<1024, 256, 0, stream>>>(qbuf, kbuf, vTs, mask, mbits, attnb);
  k_gemm<0><<<512, 256, 0, stream>>>(attnb, woutT, out, nullptr, nullptr, nullptr, nullptr, 1024);
}

// Round 22
// 181.682 us; speedup vs baseline: 1.0426x; 1.0011x over previous
//
#include <hip/hip_runtime.h>

#define BQ 4
#define SQ 2048
#define DQ 1024
#define HQ 16
#define BHQ 64

typedef __attribute__((ext_vector_type(8))) short short8;
typedef __attribute__((ext_vector_type(4))) float f32x4;
typedef __attribute__((ext_vector_type(16))) float f32x16;
typedef __attribute__((ext_vector_type(2))) unsigned int u32x2;
typedef unsigned short u16;
typedef unsigned int u32;
typedef unsigned long long u64;

__device__ __forceinline__ u16 f2bf(float f) {
  u32 u = __float_as_uint(f);
  u32 r = u + 0x7fffu + ((u >> 16) & 1u);
  return (u16)(r >> 16);
}
__device__ __forceinline__ float bf2f(u16 h) {
  return __uint_as_float(((u32)h) << 16);
}

// packed f32x2 -> bf16x2 (RNE), one instruction
__device__ __forceinline__ u32 pkbf(float lo, float hi_) {
  u32 r;
  asm("v_cvt_pk_bf16_f32 %0, %1, %2" : "=v"(r) : "v"(lo), "v"(hi_));
  return r;
}
// raw v_exp_f32: computes 2^x (input already in log2 domain)
__device__ __forceinline__ float fexp2(float x) {
  float r;
  asm("v_exp_f32 %0, %1" : "=v"(r) : "v"(x));
  return r;
}
// cross-half exchange via shfl (rare/epilogue paths only)
__device__ __forceinline__ float xmax32(float x) { return fmaxf(x, __shfl_xor(x, 32)); }
__device__ __forceinline__ float xsum32(float x) { return x + __shfl_xor(x, 32); }
// T12 primitive (m255: 1.20x vs ds_bpermute): exchange a's upper 32 lanes with b's
// lower 32 lanes. After call: a = [a.lo | b.lo], b = [a.hi | b.hi] (lane-wise).
__device__ __forceinline__ void pswap(u32& a, u32& b) {
  u32x2 r = __builtin_amdgcn_permlane32_swap(a, b, false, false);
  a = r.x;
  b = r.y;
}

// async global->LDS, 16B per lane. LDS dest must be wave-uniform; HW adds lane*16.
__device__ __forceinline__ void gload_lds16(const void* g, void* l) {
  __builtin_amdgcn_global_load_lds(
      (const __attribute__((address_space(1))) u32*)(unsigned long long)g,
      (__attribute__((address_space(3))) u32*)(u32)(unsigned long long)l,
      16, 0, 0);
}

// ---------------- fused prep: cvt x | transpose wqkv | transpose wout | rope tab | mflags ----------------
__device__ __forceinline__ void transpose_body(const float* __restrict__ in, u16* __restrict__ out,
                                               int R, int C, int bx, int by, int tid) {
  __shared__ float t[32][33];
  int c0 = bx * 32, r0 = by * 32;
  int tx = tid & 31, ty = tid >> 5;
  for (int rr = ty; rr < 32; rr += 8)
    t[rr][tx] = in[(size_t)(r0 + rr) * C + c0 + tx];
  __syncthreads();
  for (int rr = ty; rr < 32; rr += 8)
    out[(size_t)(c0 + rr) * R + r0 + tx] = f2bf(t[tx][rr]);
}

__global__ __launch_bounds__(256) void k_prep(const float* __restrict__ x, u16* __restrict__ xb,
                                              const float* __restrict__ wqkv, u16* __restrict__ wqkvT,
                                              const float* __restrict__ wout, u16* __restrict__ woutT,
                                              float* __restrict__ tab, const int* __restrict__ mask,
                                              u64* __restrict__ mbits) {
  int bid = blockIdx.x, tid = threadIdx.x;
  if (bid < 8192) {                       // cvt x -> bf16 (2M float4)
    int i = bid * 256 + tid;
    float4 v = ((const float4*)x)[i];
    ushort4 o;
    o.x = f2bf(v.x); o.y = f2bf(v.y); o.z = f2bf(v.z); o.w = f2bf(v.w);
    ((ushort4*)xb)[i] = o;
  } else if (bid < 11264) {               // transpose wqkv [1024][3072] -> [3072][1024]
    int t = bid - 8192;
    transpose_body(wqkv, wqkvT, 1024, 3072, t % 96, t / 96, tid);
  } else if (bid < 12288) {               // transpose wout [1024][1024]
    int t = bid - 11264;
    transpose_body(wout, woutT, 1024, 1024, t % 32, t / 32, tid);
  } else if (bid < 12544) {               // rope cos/sin table [S][32][2]
    int i = (bid - 12288) * 256 + tid;
    int s = i >> 5, dp = i & 31;
    float invf = expf(-0.28782313662425576f * (float)dp);
    float ang = (float)s * invf;
    tab[i * 2] = cosf(ang);
    tab[i * 2 + 1] = sinf(ang);
  } else {                                // mask bitmask (1 block: wave=batch, lane=chunk)
    int b = tid >> 6, c = tid & 63;
    int all1 = 1;
    for (int i = 0; i < 32; ++i) all1 &= (mask[b * SQ + c * 32 + i] != 0) ? 1 : 0;
    u64 m = __ballot(all1);
    if (c == 0) mbits[b] = m;
  }
}

// ---------------- GEMM v2: flash7-style single-barrier double-buffered pipeline ----------------
// BK=32, 2 LDS buffers (32KB total, occupancy unchanged). Per K-tile:
// {stage(t+1 -> buf^1) ; ds_read frags + 16 MFMA on buf ; one barrier}.
// The stage's vmcnt(0) drain lands at the NEXT barrier, after a full compute phase
// (stage latency hidden — the round-8 flash7 win, ported to GEMM).
// LDS row = 32 u16 (64B, 4 slots of 16B); (row, slot) holds source slot (slot ^ (row&3)).
// K processed in ascending 32-chunks = same accumulation order as before (bit-identical).
// 1D grid with XCD-chunked (tm,tn) map. EPI 0: f32 C. EPI 1: fused RoPE q/k + tiled K/V.
template <int EPI>
__global__ __launch_bounds__(256) void k_gemm(const u16* __restrict__ A, const u16* __restrict__ Bt,
                                              float* __restrict__ Cf, u16* __restrict__ qb,
                                              u16* __restrict__ kb, u16* __restrict__ vTs,
                                              const float* __restrict__ tab, int K) {
  __shared__ u16 lA[2][128 * 32];
  __shared__ u16 lB[2][128 * 32];
  int bid = blockIdx.x;
  int i_ = bid >> 3;
  int tm = (bid & 7) * 8 + (i_ & 7);
  int tn = i_ >> 3;
  int tid = threadIdx.x, w = tid >> 6, l = tid & 63;
  int wm = w >> 1, wn = w & 1;
  int li = l & 15, lg = l >> 4;
  const u16* gA = A + (size_t)tm * 128 * K;
  const u16* gB = Bt + (size_t)tn * 128 * K;
  f32x4 acc[4][4];
#pragma unroll
  for (int i = 0; i < 4; i++)
#pragma unroll
    for (int j = 0; j < 4; j++) acc[i][j] = (f32x4){0.f, 0.f, 0.f, 0.f};

  // staging: 2 instrs per matrix per tile; instr i covers slots i*256 + tid.
  // slot -> row = slot>>2, LDS slot index = slot&3; SOURCE col slot = (slot&3) ^ (row&3).
  int sl0 = tid, sl1 = tid + 256;
  int r0_ = sl0 >> 2, c0_ = ((sl0 & 3) ^ (r0_ & 3)) * 8;
  int r1_ = sl1 >> 2, c1_ = ((sl1 & 3) ^ (r1_ & 3)) * 8;
  const u16* aS0 = gA + (size_t)r0_ * K + c0_;
  const u16* aS1 = gA + (size_t)r1_ * K + c1_;
  const u16* bS0 = gB + (size_t)r0_ * K + c0_;
  const u16* bS1 = gB + (size_t)r1_ * K + c1_;
  // wave-uniform LDS dest bases: instr i base = i*4096B + w*1024B (lane adds l*16B)
  u16* aD0 = &lA[0][w * 64 * 8];      // u16 units: w*512
  u16* bD0 = &lB[0][w * 64 * 8];

  int NT = K >> 5;
  // prologue: stage tile 0 -> buf 0
  gload_lds16(aS0, aD0);
  gload_lds16(aS1, aD0 + 2048);
  gload_lds16(bS0, bD0);
  gload_lds16(bS1, bD0 + 2048);
  __syncthreads();

  for (int t = 0; t < NT; ++t) {
    int cur = t & 1;
    if (t + 1 < NT) {  // stage next tile into other buffer (drained at NEXT barrier)
      int off = (t + 1) * 32;
      int bo = (cur ^ 1) * 4096;  // u16 units per buffer
      gload_lds16(aS0 + off, aD0 + bo);
      gload_lds16(aS1 + off, aD0 + bo + 2048);
      gload_lds16(bS0 + off, bD0 + bo);
      gload_lds16(bS1 + off, bD0 + bo + 2048);
    }
    const u16* As = lA[cur];
    const u16* Bs = lB[cur];
    short8 af[4], bfr[4];
#pragma unroll
    for (int mf = 0; mf < 4; ++mf) {
      int row = wm * 64 + mf * 16 + li;
      af[mf] = *(const short8*)&As[row * 32 + (lg ^ (row & 3)) * 8];
    }
#pragma unroll
    for (int nf = 0; nf < 4; ++nf) {
      int row = wn * 64 + nf * 16 + li;
      bfr[nf] = *(const short8*)&Bs[row * 32 + (lg ^ (row & 3)) * 8];
    }
    __builtin_amdgcn_s_setprio(1);
#pragma unroll
    for (int mf = 0; mf < 4; ++mf)
#pragma unroll
      for (int nf = 0; nf < 4; ++nf)
        acc[mf][nf] = __builtin_amdgcn_mfma_f32_16x16x32_bf16(af[mf], bfr[nf], acc[mf][nf], 0, 0, 0);
    __builtin_amdgcn_s_setprio(0);
    __syncthreads();
  }

  if (EPI == 0) {
#pragma unroll
    for (int mf = 0; mf < 4; ++mf) {
      int mg0 = tm * 128 + wm * 64 + mf * 16 + lg * 4;
#pragma unroll
      for (int nf = 0; nf < 4; ++nf) {
        int ng = tn * 128 + wn * 64 + nf * 16 + li;
#pragma unroll
        for (int r = 0; r < 4; ++r)
          Cf[(size_t)(mg0 + r) * 1024 + ng] = acc[mf][nf][r];
      }
    }
  } else {
    int which = tn >> 3;                 // 0=q 1=k 2=v (128-col tiles, 8 per matrix)
    int h = (tn & 7) * 2 + wn;           // head
    int b = tm >> 4;                     // 128 | 2048: block never straddles batches
    if (which < 2) {
      float scale = (which == 0) ? 0.125f * 1.44269504088896f : 1.0f;
      u16* qk0 = qb + (((size_t)b * HQ + h) * SQ << 6);
      u16* kb0 = kb + ((size_t)b * HQ + h) * (64 * 2048);
#pragma unroll
      for (int mf = 0; mf < 4; ++mf) {
#pragma unroll
        for (int r = 0; r < 4; ++r) {
          int s = (tm * 128 + wm * 64 + mf * 16 + lg * 4 + r) & 2047;
#pragma unroll
          for (int nf2 = 0; nf2 < 2; ++nf2) {
            int dp = nf2 * 16 + li;      // 0..31; rope pair (dp, dp+32)
            float2 cs = *(const float2*)&tab[(s * 32 + dp) * 2];
            float a = acc[mf][nf2][r];
            float bb = acc[mf][nf2 + 2][r];
            float lo = (a * cs.x - bb * cs.y) * scale;
            float hi2 = (bb * cs.x + a * cs.y) * scale;
            if (which == 0) {
              u16* dst = qk0 + ((size_t)s << 6);
              dst[dp] = f2bf(lo);
              dst[dp + 32] = f2bf(hi2);
            } else {
              // tiled K: [kt][slot=d>>3][j=s&31][e=d&7]
              u16* dst = kb0 + (s >> 5) * 2048 + (s & 31) * 8;
              dst[(dp >> 3) * 256 + (dp & 7)] = f2bf(lo);
              dst[(dp >> 3) * 256 + 1024 + (dp & 7)] = f2bf(hi2);  // d+32 -> slot+4
            }
          }
        }
      }
    } else {
      // tiled V: [kt][slot=k>>3][d][e=k&7]; pack 4 consecutive kk -> one 8B store
#pragma unroll
      for (int mf = 0; mf < 4; ++mf) {
        int s0 = (tm * 128 + wm * 64 + mf * 16 + lg * 4) & 2047;
        int kt = s0 >> 5, kk0 = s0 & 31;
        size_t tb = (((size_t)(b * HQ + h) * 64 + kt) * 2048) + (kk0 >> 3) * 512 + (kk0 & 7);
#pragma unroll
        for (int nf = 0; nf < 4; ++nf) {
          int d = nf * 16 + li;
          u32 w0 = pkbf(acc[mf][nf][0], acc[mf][nf][1]);
          u32 w1 = pkbf(acc[mf][nf][2], acc[mf][nf][3]);
          *(u32x2*)&vTs[tb + d * 8] = (u32x2){w0, w1};
        }
      }
    }
  }
}

// ---------------- flash v13 (77.2us verified, r20): flash12 + permlane32_swap P-pack ----------------
__global__ __launch_bounds__(256) void k_flash12(const u16* __restrict__ Q, const u16* __restrict__ Kb,
                                                 const u16* __restrict__ VTs, const int* __restrict__ mask,
                                                 const u64* __restrict__ mbits, u16* __restrict__ O) {
  __shared__ alignas(16) u16 Kl[2][4096];
  __shared__ alignas(16) u16 Vl[2][4096];
  int bid = blockIdx.x;
  int bh = bid & 63;
  int u = bid >> 6, v = u & 3, k4 = u >> 2;
  int qsup = (k4 == 0) ? v : (k4 == 1) ? 7 - v : (k4 == 2) ? 8 + v : 15 - v;
  int tid = threadIdx.x, w = tid >> 6, l = tid & 63;
  int j = l & 31, hi = l >> 5;
  int myqt = qsup * 4 + w;
  int P = 2 * qsup + 2;  // phases; tiles 0..4qsup+3
  int b = bh >> 4, h = bh & 15;
  const int* mp = mask + b * SQ + 4 * hi;
  u64 mb = mbits[b];

  const u16* Kg0 = Kb + (size_t)bh * (64 * 2048) + tid * 8;   // + kt*2048
  const u16* Vg0 = VTs + (size_t)bh * (64 * 2048) + tid * 8;  // + kt*2048
  u16* KlB = &Kl[0][(size_t)w * 512];  // wave-uniform dest bases (+sub*2048, +buf*4096 u16)
  u16* VlB = &Vl[0][(size_t)w * 512];

  int qbase = myqt * 32;
  const u16* qp = Q + ((size_t)bh * SQ + qbase + j) * 64 + hi * 8;
  short8 qf[4];
#pragma unroll
  for (int kb = 0; kb < 4; ++kb) qf[kb] = *(const short8*)(qp + kb * 16);

  f32x16 o0, o1;
#pragma unroll
  for (int i = 0; i < 16; ++i) { o0[i] = 0.f; o1[i] = 0.f; }
  float mrun = -INFINITY, lrun = 0.f;

  // prologue: stage tiles 0,1 into buffer 0
  gload_lds16(Kg0, KlB);
  gload_lds16(Kg0 + 2048, KlB + 2048);
  gload_lds16(Vg0, VlB);
  gload_lds16(Vg0 + 2048, VlB + 2048);
  __syncthreads();

  for (int ph = 0; ph < P; ++ph) {
    int cur = ph & 1;
    if (ph + 1 < P) {  // stage next 2 tiles into other buffer
      const u16* kg = Kg0 + (size_t)(2 * ph + 2) * 2048;
      const u16* vg = Vg0 + (size_t)(2 * ph + 2) * 2048;
      u16* kd = KlB + (cur ^ 1) * 4096;
      u16* vd = VlB + (cur ^ 1) * 4096;
      gload_lds16(kg, kd);
      gload_lds16(kg + 2048, kd + 2048);
      gload_lds16(vg, vd);
      gload_lds16(vg + 2048, vd + 2048);
    }

#pragma unroll
    for (int sub = 0; sub < 2; ++sub) {
      int kt = 2 * ph + sub;
      if (kt <= myqt) {
        const u16* Kc = &Kl[cur][sub * 2048];
        const u16* Vc = &Vl[cur][sub * 2048];

        // K fragment: tiled [slot=hi+2kb][j][8] -> consecutive 16B across lanes
        short8 kcf[4];
#pragma unroll
        for (int kb = 0; kb < 4; ++kb)
          kcf[kb] = *(const short8*)&Kc[(hi + 2 * kb) * 256 + j * 8];

        f32x16 s;
#pragma unroll
        for (int i = 0; i < 16; ++i) s[i] = 0.f;
        __builtin_amdgcn_s_setprio(1);
#pragma unroll
        for (int kb = 0; kb < 4; ++kb)
          s = __builtin_amdgcn_mfma_f32_32x32x16_bf16(kcf[kb], qf[kb], s, 0, 0, 0);
        __builtin_amdgcn_s_setprio(0);

        // V fragments: tiled [slot][d][8]
        short8 va0 = *(const short8*)&Vc[hi * 512 + j * 8];
        short8 va1 = *(const short8*)&Vc[(hi + 2) * 512 + j * 8];
        short8 vb0 = *(const short8*)&Vc[hi * 512 + (j + 32) * 8];
        short8 vb1 = *(const short8*)&Vc[(hi + 2) * 512 + (j + 32) * 8];

        // pad mask: only when this 32-chunk has zeros (never in this harness)
        if (!((mb >> kt) & 1ull)) {
#pragma unroll
          for (int rq = 0; rq < 4; ++rq) {
            int4 mv = *(const int4*)(mp + kt * 32 + 8 * rq);
            if (!mv.x) s[4 * rq + 0] = -INFINITY;
            if (!mv.y) s[4 * rq + 1] = -INFINITY;
            if (!mv.z) s[4 * rq + 2] = -INFINITY;
            if (!mv.w) s[4 * rq + 3] = -INFINITY;
          }
        }
        // causal: diagonal tile masks k>q
        if (kt == myqt) {
#pragma unroll
          for (int rq = 0; rq < 4; ++rq)
#pragma unroll
            for (int t = 0; t < 4; ++t)
              if (8 * rq + 4 * hi + t > j) s[4 * rq + t] = -INFINITY;
        }

        // online softmax in log2 domain, fully in-register
        float t0 = fmaxf(fmaxf(fmaxf(s[0], s[1]), fmaxf(s[2], s[3])),
                         fmaxf(fmaxf(s[4], s[5]), fmaxf(s[6], s[7])));
        t0 = fmaxf(t0, fmaxf(fmaxf(fmaxf(s[8], s[9]), fmaxf(s[10], s[11])),
                             fmaxf(fmaxf(s[12], s[13]), fmaxf(s[14], s[15]))));
        if (!__all(t0 <= mrun + 8.0f)) {  // defer-max (T13)
          float tm2 = xmax32(t0);
          float mn = fmaxf(fmaxf(mrun, tm2), -1e30f);
          float alpha = fexp2(mrun - mn);
          mrun = mn;
          lrun *= alpha;
#pragma unroll
          for (int i = 0; i < 16; ++i) { o0[i] *= alpha; o1[i] *= alpha; }
        }
        float ts = 0.f;
#pragma unroll
        for (int i = 0; i < 16; ++i) {
          float pv = fexp2(s[i] - mrun);
          s[i] = pv;
          ts += pv;
        }
        lrun += ts;

        // pack P^T into B fragments: cvt_pk pairs + permlane32_swap (T12, no selects)
        u32 pa[4], pb[4];
#pragma unroll
        for (int q2 = 0; q2 < 4; ++q2) {
          pa[q2] = pkbf(s[4 * q2 + 0], s[4 * q2 + 1]);
          pb[q2] = pkbf(s[4 * q2 + 2], s[4 * q2 + 3]);
        }
        pswap(pa[0], pa[1]);
        pswap(pb[0], pb[1]);
        pswap(pa[2], pa[3]);
        pswap(pb[2], pb[3]);
        union { short8 s8; u32 wd[4]; } f0, f1;
        f0.wd[0] = pa[0];
        f0.wd[1] = pb[0];
        f0.wd[2] = pa[1];
        f0.wd[3] = pb[1];
        f1.wd[0] = pa[2];
        f1.wd[1] = pb[2];
        f1.wd[2] = pa[3];
        f1.wd[3] = pb[3];

        // PV: O^T += V^T(frag A) x P^T(frag B)
        __builtin_amdgcn_s_setprio(1);
        o0 = __builtin_amdgcn_mfma_f32_32x32x16_bf16(va0, f0.s8, o0, 0, 0, 0);
        o0 = __builtin_amdgcn_mfma_f32_32x32x16_bf16(va1, f1.s8, o0, 0, 0, 0);
        o1 = __builtin_amdgcn_mfma_f32_32x32x16_bf16(vb0, f0.s8, o1, 0, 0, 0);
        o1 = __builtin_amdgcn_mfma_f32_32x32x16_bf16(vb1, f1.s8, o1, 0, 0, 0);
        __builtin_amdgcn_s_setprio(0);
      }
    }

    __syncthreads();  // drains vmem (next stage) + all waves done reading cur
  }

  // epilogue: merge the two halves' lrun, store q rows
  float lfull = xsum32(lrun);
  float inv = 1.0f / lfull;
  u16* ob = O + ((size_t)b * SQ + qbase + j) * DQ + h * 64 + 4 * hi;
#pragma unroll
  for (int q2 = 0; q2 < 4; ++q2) {
#pragma unroll
    for (int e = 0; e < 2; ++e) {
      *(u32*)(ob + 8 * q2 + 2 * e) = pkbf(o0[4 * q2 + 2 * e] * inv, o0[4 * q2 + 2 * e + 1] * inv);
      *(u32*)(ob + 32 + 8 * q2 + 2 * e) = pkbf(o1[4 * q2 + 2 * e] * inv, o1[4 * q2 + 2 * e + 1] * inv);
    }
  }
}

extern "C" void kernel_launch(void* const* d_in, const int* in_sizes, int n_in,
                              void* d_out, int out_size, void* d_ws, size_t ws_size,
                              hipStream_t stream) {
  const float* x = (const float*)d_in[0];
  const int* mask = (const int*)d_in[1];
  const float* wqkv = (const float*)d_in[2];
  const float* wout = (const float*)d_in[3];
  float* out = (float*)d_out;
  char* ws = (char*)d_ws;

  u16* xb    = (u16*)(ws + 0);           // 16 MB
  u16* wqkvT = (u16*)(ws + 16777216);    // 6 MB  [3072][1024]
  u16* woutT = (u16*)(ws + 23068672);    // 2 MB  [1024][1024]
  u16* qbuf  = (u16*)(ws + 25165824);    // 16 MB [bh][S][64]
  u16* kbuf  = (u16*)(ws + 41943040);    // 16 MB [bh][64 kt][8 slot][32 j][8] tiled
  u16* vTs   = (u16*)(ws + 75497472);    // 16 MB [bh][64 kt][4 slot][64 d][8] tiled
  u16* attnb = (u16*)(ws + 92274688);    // 16 MB [B*S][1024]
  float* tab = (float*)(ws + 109051904); // 512 KB
  u64* mbits = (u64*)(ws + 109576192);   // 32 B

  k_prep<<<12545, 256, 0, stream>>>(x, xb, wqkv, wqkvT, wout, woutT, tab, mask, mbits);
  k_gemm<1><<<1536, 256, 0, stream>>>(xb, wqkvT, nullptr, qbuf, kbuf, vTs, tab, 1024);
  k_flash12<<<1024, 256, 0, stream>>>(qbuf, kbuf, vTs, mask, mbits, attnb);
  k_gemm<0><<<512, 256, 0, stream>>>(attnb, woutT, out, nullptr, nullptr, nullptr, nullptr, 1024);
}

// Round 23
// 177.478 us; speedup vs baseline: 1.0673x; 1.0237x over previous
//
#include <hip/hip_runtime.h>

#define BQ 4
#define SQ 2048
#define DQ 1024
#define HQ 16
#define BHQ 64

typedef __attribute__((ext_vector_type(8))) short short8;
typedef __attribute__((ext_vector_type(4))) float f32x4;
typedef __attribute__((ext_vector_type(16))) float f32x16;
typedef __attribute__((ext_vector_type(2))) unsigned int u32x2;
typedef unsigned short u16;
typedef unsigned int u32;
typedef unsigned long long u64;

__device__ __forceinline__ u16 f2bf(float f) {
  u32 u = __float_as_uint(f);
  u32 r = u + 0x7fffu + ((u >> 16) & 1u);
  return (u16)(r >> 16);
}
__device__ __forceinline__ float bf2f(u16 h) {
  return __uint_as_float(((u32)h) << 16);
}

// packed f32x2 -> bf16x2 (RNE), one instruction
__device__ __forceinline__ u32 pkbf(float lo, float hi_) {
  u32 r;
  asm("v_cvt_pk_bf16_f32 %0, %1, %2" : "=v"(r) : "v"(lo), "v"(hi_));
  return r;
}
// raw v_exp_f32: computes 2^x (input already in log2 domain)
__device__ __forceinline__ float fexp2(float x) {
  float r;
  asm("v_exp_f32 %0, %1" : "=v"(r) : "v"(x));
  return r;
}
// 3-input max, single VOP3 instruction (T17)
__device__ __forceinline__ float fmax3(float a, float b, float c) {
  float r;
  asm("v_max3_f32 %0, %1, %2, %3" : "=v"(r) : "v"(a), "v"(b), "v"(c));
  return r;
}
// cross-half exchange via shfl (rare/epilogue paths only)
__device__ __forceinline__ float xmax32(float x) { return fmaxf(x, __shfl_xor(x, 32)); }
__device__ __forceinline__ float xsum32(float x) { return x + __shfl_xor(x, 32); }
// T12 primitive (m255: 1.20x vs ds_bpermute): exchange a's upper 32 lanes with b's
// lower 32 lanes. After call: a = [a.lo | b.lo], b = [a.hi | b.hi] (lane-wise).
__device__ __forceinline__ void pswap(u32& a, u32& b) {
  u32x2 r = __builtin_amdgcn_permlane32_swap(a, b, false, false);
  a = r.x;
  b = r.y;
}

// async global->LDS, 16B per lane. LDS dest must be wave-uniform; HW adds lane*16.
__device__ __forceinline__ void gload_lds16(const void* g, void* l) {
  __builtin_amdgcn_global_load_lds(
      (const __attribute__((address_space(1))) u32*)(unsigned long long)g,
      (__attribute__((address_space(3))) u32*)(u32)(unsigned long long)l,
      16, 0, 0);
}

// ---------------- fused prep: cvt x | transpose wqkv | transpose wout | rope tab | mflags ----------------
__device__ __forceinline__ void transpose_body(const float* __restrict__ in, u16* __restrict__ out,
                                               int R, int C, int bx, int by, int tid) {
  __shared__ float t[32][33];
  int c0 = bx * 32, r0 = by * 32;
  int tx = tid & 31, ty = tid >> 5;
  for (int rr = ty; rr < 32; rr += 8)
    t[rr][tx] = in[(size_t)(r0 + rr) * C + c0 + tx];
  __syncthreads();
  for (int rr = ty; rr < 32; rr += 8)
    out[(size_t)(c0 + rr) * R + r0 + tx] = f2bf(t[tx][rr]);
}

__global__ __launch_bounds__(256) void k_prep(const float* __restrict__ x, u16* __restrict__ xb,
                                              const float* __restrict__ wqkv, u16* __restrict__ wqkvT,
                                              const float* __restrict__ wout, u16* __restrict__ woutT,
                                              float* __restrict__ tab, const int* __restrict__ mask,
                                              u64* __restrict__ mbits) {
  int bid = blockIdx.x, tid = threadIdx.x;
  if (bid < 8192) {                       // cvt x -> bf16 (2M float4)
    int i = bid * 256 + tid;
    float4 v = ((const float4*)x)[i];
    ushort4 o;
    o.x = f2bf(v.x); o.y = f2bf(v.y); o.z = f2bf(v.z); o.w = f2bf(v.w);
    ((ushort4*)xb)[i] = o;
  } else if (bid < 11264) {               // transpose wqkv [1024][3072] -> [3072][1024]
    int t = bid - 8192;
    transpose_body(wqkv, wqkvT, 1024, 3072, t % 96, t / 96, tid);
  } else if (bid < 12288) {               // transpose wout [1024][1024]
    int t = bid - 11264;
    transpose_body(wout, woutT, 1024, 1024, t % 32, t / 32, tid);
  } else if (bid < 12544) {               // rope cos/sin table [S][32][2]
    int i = (bid - 12288) * 256 + tid;
    int s = i >> 5, dp = i & 31;
    float invf = expf(-0.28782313662425576f * (float)dp);
    float ang = (float)s * invf;
    tab[i * 2] = cosf(ang);
    tab[i * 2 + 1] = sinf(ang);
  } else {                                // mask bitmask (1 block: wave=batch, lane=chunk)
    int b = tid >> 6, c = tid & 63;
    int all1 = 1;
    for (int i = 0; i < 32; ++i) all1 &= (mask[b * SQ + c * 32 + i] != 0) ? 1 : 0;
    u64 m = __ballot(all1);
    if (c == 0) mbits[b] = m;
  }
}

// ---------------- GEMM v2: flash7-style single-barrier double-buffered pipeline ----------------
// BK=32, 2 LDS buffers (32KB total). Per K-tile: {stage(t+1 -> buf^1) ; compute(buf) ; barrier}.
// Stage drain lands at the NEXT barrier, after a full compute phase (latency hidden).
// LDS row = 32 u16 (64B, 4 slots); (row, slot) holds source slot (slot ^ (row&3)).
// 1D grid with XCD-chunked (tm,tn) map. EPI 0: f32 C. EPI 1: fused RoPE q/k + tiled K/V.
template <int EPI>
__global__ __launch_bounds__(256) void k_gemm(const u16* __restrict__ A, const u16* __restrict__ Bt,
                                              float* __restrict__ Cf, u16* __restrict__ qb,
                                              u16* __restrict__ kb, u16* __restrict__ vTs,
                                              const float* __restrict__ tab, int K) {
  __shared__ u16 lA[2][128 * 32];
  __shared__ u16 lB[2][128 * 32];
  int bid = blockIdx.x;
  int i_ = bid >> 3;
  int tm = (bid & 7) * 8 + (i_ & 7);
  int tn = i_ >> 3;
  int tid = threadIdx.x, w = tid >> 6, l = tid & 63;
  int wm = w >> 1, wn = w & 1;
  int li = l & 15, lg = l >> 4;
  const u16* gA = A + (size_t)tm * 128 * K;
  const u16* gB = Bt + (size_t)tn * 128 * K;
  f32x4 acc[4][4];
#pragma unroll
  for (int i = 0; i < 4; i++)
#pragma unroll
    for (int j = 0; j < 4; j++) acc[i][j] = (f32x4){0.f, 0.f, 0.f, 0.f};

  int sl0 = tid, sl1 = tid + 256;
  int r0_ = sl0 >> 2, c0_ = ((sl0 & 3) ^ (r0_ & 3)) * 8;
  int r1_ = sl1 >> 2, c1_ = ((sl1 & 3) ^ (r1_ & 3)) * 8;
  const u16* aS0 = gA + (size_t)r0_ * K + c0_;
  const u16* aS1 = gA + (size_t)r1_ * K + c1_;
  const u16* bS0 = gB + (size_t)r0_ * K + c0_;
  const u16* bS1 = gB + (size_t)r1_ * K + c1_;
  u16* aD0 = &lA[0][w * 64 * 8];      // u16 units: w*512
  u16* bD0 = &lB[0][w * 64 * 8];

  int NT = K >> 5;
  gload_lds16(aS0, aD0);
  gload_lds16(aS1, aD0 + 2048);
  gload_lds16(bS0, bD0);
  gload_lds16(bS1, bD0 + 2048);
  __syncthreads();

  for (int t = 0; t < NT; ++t) {
    int cur = t & 1;
    if (t + 1 < NT) {  // stage next tile into other buffer (drained at NEXT barrier)
      int off = (t + 1) * 32;
      int bo = (cur ^ 1) * 4096;  // u16 units per buffer
      gload_lds16(aS0 + off, aD0 + bo);
      gload_lds16(aS1 + off, aD0 + bo + 2048);
      gload_lds16(bS0 + off, bD0 + bo);
      gload_lds16(bS1 + off, bD0 + bo + 2048);
    }
    const u16* As = lA[cur];
    const u16* Bs = lB[cur];
    short8 af[4], bfr[4];
#pragma unroll
    for (int mf = 0; mf < 4; ++mf) {
      int row = wm * 64 + mf * 16 + li;
      af[mf] = *(const short8*)&As[row * 32 + (lg ^ (row & 3)) * 8];
    }
#pragma unroll
    for (int nf = 0; nf < 4; ++nf) {
      int row = wn * 64 + nf * 16 + li;
      bfr[nf] = *(const short8*)&Bs[row * 32 + (lg ^ (row & 3)) * 8];
    }
    __builtin_amdgcn_s_setprio(1);
#pragma unroll
    for (int mf = 0; mf < 4; ++mf)
#pragma unroll
      for (int nf = 0; nf < 4; ++nf)
        acc[mf][nf] = __builtin_amdgcn_mfma_f32_16x16x32_bf16(af[mf], bfr[nf], acc[mf][nf], 0, 0, 0);
    __builtin_amdgcn_s_setprio(0);
    __syncthreads();
  }

  if (EPI == 0) {
#pragma unroll
    for (int mf = 0; mf < 4; ++mf) {
      int mg0 = tm * 128 + wm * 64 + mf * 16 + lg * 4;
#pragma unroll
      for (int nf = 0; nf < 4; ++nf) {
        int ng = tn * 128 + wn * 64 + nf * 16 + li;
#pragma unroll
        for (int r = 0; r < 4; ++r)
          Cf[(size_t)(mg0 + r) * 1024 + ng] = acc[mf][nf][r];
      }
    }
  } else {
    int which = tn >> 3;                 // 0=q 1=k 2=v (128-col tiles, 8 per matrix)
    int h = (tn & 7) * 2 + wn;           // head
    int b = tm >> 4;                     // 128 | 2048: block never straddles batches
    if (which < 2) {
      float scale = (which == 0) ? 0.125f * 1.44269504088896f : 1.0f;
      u16* qk0 = qb + (((size_t)b * HQ + h) * SQ << 6);
      u16* kb0 = kb + ((size_t)b * HQ + h) * (64 * 2048);
#pragma unroll
      for (int mf = 0; mf < 4; ++mf) {
#pragma unroll
        for (int r = 0; r < 4; ++r) {
          int s = (tm * 128 + wm * 64 + mf * 16 + lg * 4 + r) & 2047;
#pragma unroll
          for (int nf2 = 0; nf2 < 2; ++nf2) {
            int dp = nf2 * 16 + li;      // 0..31; rope pair (dp, dp+32)
            float2 cs = *(const float2*)&tab[(s * 32 + dp) * 2];
            float a = acc[mf][nf2][r];
            float bb = acc[mf][nf2 + 2][r];
            float lo = (a * cs.x - bb * cs.y) * scale;
            float hi2 = (bb * cs.x + a * cs.y) * scale;
            if (which == 0) {
              u16* dst = qk0 + ((size_t)s << 6);
              dst[dp] = f2bf(lo);
              dst[dp + 32] = f2bf(hi2);
            } else {
              // tiled K: [kt][slot=d>>3][j=s&31][e=d&7]
              u16* dst = kb0 + (s >> 5) * 2048 + (s & 31) * 8;
              dst[(dp >> 3) * 256 + (dp & 7)] = f2bf(lo);
              dst[(dp >> 3) * 256 + 1024 + (dp & 7)] = f2bf(hi2);  // d+32 -> slot+4
            }
          }
        }
      }
    } else {
      // tiled V: [kt][slot=k>>3][d][e=k&7]; pack 4 consecutive kk -> one 8B store
#pragma unroll
      for (int mf = 0; mf < 4; ++mf) {
        int s0 = (tm * 128 + wm * 64 + mf * 16 + lg * 4) & 2047;
        int kt = s0 >> 5, kk0 = s0 & 31;
        size_t tb = (((size_t)(b * HQ + h) * 64 + kt) * 2048) + (kk0 >> 3) * 512 + (kk0 & 7);
#pragma unroll
        for (int nf = 0; nf < 4; ++nf) {
          int d = nf * 16 + li;
          u32 w0 = pkbf(acc[mf][nf][0], acc[mf][nf][1]);
          u32 w1 = pkbf(acc[mf][nf][2], acc[mf][nf][3]);
          *(u32x2*)&vTs[tb + d * 8] = (u32x2){w0, w1};
        }
      }
    }
  }
}

// ---------------- flash v13 + v_max3 softmax tree (T17) ----------------
// Identical to the verified round-22 kernel except the 16-value max reduction:
// 15 pairwise v_max -> 7 v_max3 + 1 v_max (same max, fmax associative, bit-identical).
__global__ __launch_bounds__(256) void k_flash12(const u16* __restrict__ Q, const u16* __restrict__ Kb,
                                                 const u16* __restrict__ VTs, const int* __restrict__ mask,
                                                 const u64* __restrict__ mbits, u16* __restrict__ O) {
  __shared__ alignas(16) u16 Kl[2][4096];
  __shared__ alignas(16) u16 Vl[2][4096];
  int bid = blockIdx.x;
  int bh = bid & 63;
  int u = bid >> 6, v = u & 3, k4 = u >> 2;
  int qsup = (k4 == 0) ? v : (k4 == 1) ? 7 - v : (k4 == 2) ? 8 + v : 15 - v;
  int tid = threadIdx.x, w = tid >> 6, l = tid & 63;
  int j = l & 31, hi = l >> 5;
  int myqt = qsup * 4 + w;
  int P = 2 * qsup + 2;  // phases; tiles 0..4qsup+3
  int b = bh >> 4, h = bh & 15;
  const int* mp = mask + b * SQ + 4 * hi;
  u64 mb = mbits[b];

  const u16* Kg0 = Kb + (size_t)bh * (64 * 2048) + tid * 8;   // + kt*2048
  const u16* Vg0 = VTs + (size_t)bh * (64 * 2048) + tid * 8;  // + kt*2048
  u16* KlB = &Kl[0][(size_t)w * 512];  // wave-uniform dest bases (+sub*2048, +buf*4096 u16)
  u16* VlB = &Vl[0][(size_t)w * 512];

  int qbase = myqt * 32;
  const u16* qp = Q + ((size_t)bh * SQ + qbase + j) * 64 + hi * 8;
  short8 qf[4];
#pragma unroll
  for (int kb = 0; kb < 4; ++kb) qf[kb] = *(const short8*)(qp + kb * 16);

  f32x16 o0, o1;
#pragma unroll
  for (int i = 0; i < 16; ++i) { o0[i] = 0.f; o1[i] = 0.f; }
  float mrun = -INFINITY, lrun = 0.f;

  // prologue: stage tiles 0,1 into buffer 0
  gload_lds16(Kg0, KlB);
  gload_lds16(Kg0 + 2048, KlB + 2048);
  gload_lds16(Vg0, VlB);
  gload_lds16(Vg0 + 2048, VlB + 2048);
  __syncthreads();

  for (int ph = 0; ph < P; ++ph) {
    int cur = ph & 1;
    if (ph + 1 < P) {  // stage next 2 tiles into other buffer
      const u16* kg = Kg0 + (size_t)(2 * ph + 2) * 2048;
      const u16* vg = Vg0 + (size_t)(2 * ph + 2) * 2048;
      u16* kd = KlB + (cur ^ 1) * 4096;
      u16* vd = VlB + (cur ^ 1) * 4096;
      gload_lds16(kg, kd);
      gload_lds16(kg + 2048, kd + 2048);
      gload_lds16(vg, vd);
      gload_lds16(vg + 2048, vd + 2048);
    }

#pragma unroll
    for (int sub = 0; sub < 2; ++sub) {
      int kt = 2 * ph + sub;
      if (kt <= myqt) {
        const u16* Kc = &Kl[cur][sub * 2048];
        const u16* Vc = &Vl[cur][sub * 2048];

        // K fragment: tiled [slot=hi+2kb][j][8] -> consecutive 16B across lanes
        short8 kcf[4];
#pragma unroll
        for (int kb = 0; kb < 4; ++kb)
          kcf[kb] = *(const short8*)&Kc[(hi + 2 * kb) * 256 + j * 8];

        f32x16 s;
#pragma unroll
        for (int i = 0; i < 16; ++i) s[i] = 0.f;
        __builtin_amdgcn_s_setprio(1);
#pragma unroll
        for (int kb = 0; kb < 4; ++kb)
          s = __builtin_amdgcn_mfma_f32_32x32x16_bf16(kcf[kb], qf[kb], s, 0, 0, 0);
        __builtin_amdgcn_s_setprio(0);

        // V fragments: tiled [slot][d][8]
        short8 va0 = *(const short8*)&Vc[hi * 512 + j * 8];
        short8 va1 = *(const short8*)&Vc[(hi + 2) * 512 + j * 8];
        short8 vb0 = *(const short8*)&Vc[hi * 512 + (j + 32) * 8];
        short8 vb1 = *(const short8*)&Vc[(hi + 2) * 512 + (j + 32) * 8];

        // pad mask: only when this 32-chunk has zeros (never in this harness)
        if (!((mb >> kt) & 1ull)) {
#pragma unroll
          for (int rq = 0; rq < 4; ++rq) {
            int4 mv = *(const int4*)(mp + kt * 32 + 8 * rq);
            if (!mv.x) s[4 * rq + 0] = -INFINITY;
            if (!mv.y) s[4 * rq + 1] = -INFINITY;
            if (!mv.z) s[4 * rq + 2] = -INFINITY;
            if (!mv.w) s[4 * rq + 3] = -INFINITY;
          }
        }
        // causal: diagonal tile masks k>q
        if (kt == myqt) {
#pragma unroll
          for (int rq = 0; rq < 4; ++rq)
#pragma unroll
            for (int t = 0; t < 4; ++t)
              if (8 * rq + 4 * hi + t > j) s[4 * rq + t] = -INFINITY;
        }

        // online softmax in log2 domain; max via v_max3 tree (T17)
        float m0 = fmax3(s[0], s[1], s[2]);
        float m1 = fmax3(s[3], s[4], s[5]);
        float m2 = fmax3(s[6], s[7], s[8]);
        float m3 = fmax3(s[9], s[10], s[11]);
        float m4 = fmax3(s[12], s[13], s[14]);
        float t0 = fmaxf(fmax3(m0, m1, m2), fmax3(m3, m4, s[15]));
        if (!__all(t0 <= mrun + 8.0f)) {  // defer-max (T13)
          float tm2 = xmax32(t0);
          float mn = fmaxf(fmaxf(mrun, tm2), -1e30f);
          float alpha = fexp2(mrun - mn);
          mrun = mn;
          lrun *= alpha;
#pragma unroll
          for (int i = 0; i < 16; ++i) { o0[i] *= alpha; o1[i] *= alpha; }
        }
        float ts = 0.f;
#pragma unroll
        for (int i = 0; i < 16; ++i) {
          float pv = fexp2(s[i] - mrun);
          s[i] = pv;
          ts += pv;
        }
        lrun += ts;

        // pack P^T into B fragments: cvt_pk pairs + permlane32_swap (T12, no selects)
        u32 pa[4], pb[4];
#pragma unroll
        for (int q2 = 0; q2 < 4; ++q2) {
          pa[q2] = pkbf(s[4 * q2 + 0], s[4 * q2 + 1]);
          pb[q2] = pkbf(s[4 * q2 + 2], s[4 * q2 + 3]);
        }
        pswap(pa[0], pa[1]);
        pswap(pb[0], pb[1]);
        pswap(pa[2], pa[3]);
        pswap(pb[2], pb[3]);
        union { short8 s8; u32 wd[4]; } f0, f1;
        f0.wd[0] = pa[0];
        f0.wd[1] = pb[0];
        f0.wd[2] = pa[1];
        f0.wd[3] = pb[1];
        f1.wd[0] = pa[2];
        f1.wd[1] = pb[2];
        f1.wd[2] = pa[3];
        f1.wd[3] = pb[3];

        // PV: O^T += V^T(frag A) x P^T(frag B)
        __builtin_amdgcn_s_setprio(1);
        o0 = __builtin_amdgcn_mfma_f32_32x32x16_bf16(va0, f0.s8, o0, 0, 0, 0);
        o0 = __builtin_amdgcn_mfma_f32_32x32x16_bf16(va1, f1.s8, o0, 0, 0, 0);
        o1 = __builtin_amdgcn_mfma_f32_32x32x16_bf16(vb0, f0.s8, o1, 0, 0, 0);
        o1 = __builtin_amdgcn_mfma_f32_32x32x16_bf16(vb1, f1.s8, o1, 0, 0, 0);
        __builtin_amdgcn_s_setprio(0);
      }
    }

    __syncthreads();  // drains vmem (next stage) + all waves done reading cur
  }

  // epilogue: merge the two halves' lrun, store q rows
  float lfull = xsum32(lrun);
  float inv = 1.0f / lfull;
  u16* ob = O + ((size_t)b * SQ + qbase + j) * DQ + h * 64 + 4 * hi;
#pragma unroll
  for (int q2 = 0; q2 < 4; ++q2) {
#pragma unroll
    for (int e = 0; e < 2; ++e) {
      *(u32*)(ob + 8 * q2 + 2 * e) = pkbf(o0[4 * q2 + 2 * e] * inv, o0[4 * q2 + 2 * e + 1] * inv);
      *(u32*)(ob + 32 + 8 * q2 + 2 * e) = pkbf(o1[4 * q2 + 2 * e] * inv, o1[4 * q2 + 2 * e + 1] * inv);
    }
  }
}

extern "C" void kernel_launch(void* const* d_in, const int* in_sizes, int n_in,
                              void* d_out, int out_size, void* d_ws, size_t ws_size,
                              hipStream_t stream) {
  const float* x = (const float*)d_in[0];
  const int* mask = (const int*)d_in[1];
  const float* wqkv = (const float*)d_in[2];
  const float* wout = (const float*)d_in[3];
  float* out = (float*)d_out;
  char* ws = (char*)d_ws;

  u16* xb    = (u16*)(ws + 0);           // 16 MB
  u16* wqkvT = (u16*)(ws + 16777216);    // 6 MB  [3072][1024]
  u16* woutT = (u16*)(ws + 23068672);    // 2 MB  [1024][1024]
  u16* qbuf  = (u16*)(ws + 25165824);    // 16 MB [bh][S][64]
  u16* kbuf  = (u16*)(ws + 41943040);    // 16 MB [bh][64 kt][8 slot][32 j][8] tiled
  u16* vTs   = (u16*)(ws + 75497472);    // 16 MB [bh][64 kt][4 slot][64 d][8] tiled
  u16* attnb = (u16*)(ws + 92274688);    // 16 MB [B*S][1024]
  float* tab = (float*)(ws + 109051904); // 512 KB
  u64* mbits = (u64*)(ws + 109576192);   // 32 B

  k_prep<<<12545, 256, 0, stream>>>(x, xb, wqkv, wqkvT, wout, woutT, tab, mask, mbits);
  k_gemm<1><<<1536, 256, 0, stream>>>(xb, wqkvT, nullptr, qbuf, kbuf, vTs, tab, 1024);
  k_flash12<<<1024, 256, 0, stream>>>(qbuf, kbuf, vTs, mask, mbits, attnb);
  k_gemm<0><<<512, 256, 0, stream>>>(attnb, woutT, out, nullptr, nullptr, nullptr, nullptr, 1024);
}